// Round 12
// baseline (645.383 us; speedup 1.0000x reference)
//
#include <hip/hip_runtime.h>
#include <hip/hip_fp16.h>

// N=100000 nodes, E=1000000 edges, D_IN=16, H=2, C=64.
// 3x (GAT -> BN -> ReLU), then MLP head -> (logits, value) concat in d_out.
// hbuf fp16; edge scores precomputed edge-parallel; aggregation walks
// 8 edges per wave-iteration (8 lanes/edge, 32 B/lane). BN apply is fused
// into the consumers (project A-staging / mlp a1-staging) via scsh[128].
// CSR via binned counting sort (streaming writes).

__device__ __forceinline__ float leaky(float x) { return x > 0.f ? x : 0.2f * x; }

#define BCAP 4096  // max edges per 256-dst bucket (mean ~2560)

// ---------------- CSR build ----------------
__global__ void bucket_hist(const int* __restrict__ dst, int* __restrict__ bcnt, int E) {
  __shared__ int cnt[512];
  int t = threadIdx.x;
  cnt[t] = 0; cnt[t + 256] = 0;
  __syncthreads();
  for (int e = blockIdx.x * blockDim.x + t; e < E; e += gridDim.x * blockDim.x)
    atomicAdd(&cnt[dst[e] >> 8], 1);
  __syncthreads();
  for (int i = t; i < 512; i += 256)
    if (cnt[i]) atomicAdd(&bcnt[i], cnt[i]);
}

__global__ void bucket_scan(const int* __restrict__ bcnt, int* __restrict__ boff,
                            int* __restrict__ bcur, int nbk) {
  __shared__ int temp[512];
  int t = threadIdx.x;  // 512 threads
  int v = (t < nbk) ? bcnt[t] : 0;
  temp[t] = v;
  __syncthreads();
  for (int off = 1; off < 512; off <<= 1) {
    int add = (t >= off) ? temp[t - off] : 0;
    __syncthreads();
    temp[t] += add;
    __syncthreads();
  }
  if (t < nbk) {
    int ex = temp[t] - v;
    boff[t] = ex;
    bcur[t] = ex;
  }
}

__global__ __launch_bounds__(256) void bin_scatter(
    const int* __restrict__ src, const int* __restrict__ dst,
    int* __restrict__ bcur, int2* __restrict__ ebuf, int E) {
  __shared__ int cnt[512];
  __shared__ int base[512];
  int t = threadIdx.x;
  int beg = blockIdx.x * 8192;
  int end = min(E, beg + 8192);
  cnt[t] = 0; cnt[t + 256] = 0;
  __syncthreads();
  for (int e = beg + t; e < end; e += 256)
    atomicAdd(&cnt[dst[e] >> 8], 1);
  __syncthreads();
  for (int i = t; i < 512; i += 256) {
    base[i] = cnt[i] ? atomicAdd(&bcur[i], cnt[i]) : 0;
    cnt[i] = 0;  // reuse as within-run cursor
  }
  __syncthreads();
  for (int e = beg + t; e < end; e += 256) {
    int d = dst[e];
    int bk = d >> 8;
    int off = atomicAdd(&cnt[bk], 1);
    ebuf[base[bk] + off] = make_int2(src[e], d);
  }
}

__global__ __launch_bounds__(256) void bucket_sort(
    const int2* __restrict__ ebuf, const int* __restrict__ boff,
    int2* __restrict__ col2, int* __restrict__ row_ptr, int E, int n, int nbk) {
  __shared__ int2 eds[BCAP];
  __shared__ int dcnt[256];
  __shared__ int dbase[256];
  __shared__ int dexcl[256];
  int b = blockIdx.x, t = threadIdx.x;
  int S = boff[b];
  int Eend = (b + 1 < nbk) ? boff[b + 1] : E;
  int cnt = min(Eend - S, BCAP);
  for (int i = t; i < cnt; i += 256) eds[i] = ebuf[S + i];
  dcnt[t] = 0;
  __syncthreads();
  for (int i = t; i < cnt; i += 256) atomicAdd(&dcnt[eds[i].y & 255], 1);
  __syncthreads();
  int v = dcnt[t];
  dbase[t] = v;
  __syncthreads();
  for (int off = 1; off < 256; off <<= 1) {
    int add = (t >= off) ? dbase[t - off] : 0;
    __syncthreads();
    dbase[t] += add;
    __syncthreads();
  }
  int excl = dbase[t] - v;
  int d = (b << 8) + t;
  if (d < n) row_ptr[d] = S + excl;
  if (b == nbk - 1 && t == 0) row_ptr[n] = E;
  dcnt[t] = 0;  // reuse as per-dst cursor
  dexcl[t] = excl;
  __syncthreads();
  for (int i = t; i < cnt; i += 256) {
    int2 e = eds[i];
    int dl = e.y & 255;
    int off = atomicAdd(&dcnt[dl], 1);
    col2[S + dexcl[dl] + off] = e;
  }
}

// ---------------- edge-parallel softmax numerators -------------------------
__global__ void edge_scores(const int2* __restrict__ col2,
                            const float* __restrict__ as_, const float* __restrict__ ad_,
                            float2* __restrict__ ee, int M) {
  int p = blockIdx.x * blockDim.x + threadIdx.x;
  if (p >= M) return;
  int2 sd = col2[p];
  float2 a = *(const float2*)&as_[sd.x * 2];
  float2 b = *(const float2*)&ad_[sd.y * 2];
  float2 r;
  r.x = __expf(leaky(a.x + b.x));
  r.y = __expf(leaky(a.y + b.y));
  ee[p] = r;
}

// ---------------- BN stats + finalize ----------------
__global__ void bn_stats(const float* __restrict__ h, float* __restrict__ stats, int n) {
  __shared__ float ssum[64], ssq[64];
  int t = threadIdx.x;
  if (t < 64) { ssum[t] = 0.f; ssq[t] = 0.f; }
  __syncthreads();
  int c = t & 63;
  float lsum = 0.f, lsq = 0.f;
  size_t total = (size_t)n * 64;
  for (size_t i = (size_t)blockIdx.x * blockDim.x + t; i < total;
       i += (size_t)gridDim.x * blockDim.x) {
    float v = h[i];
    lsum += v;
    lsq = fmaf(v, v, lsq);
  }
  atomicAdd(&ssum[c], lsum);
  atomicAdd(&ssq[c], lsq);
  __syncthreads();
  if (t < 64) {
    atomicAdd(&stats[t], ssum[t]);
    atomicAdd(&stats[64 + t], ssq[t]);
  }
}

// scsh[c] = scale, scsh[64+c] = shift so that bn(v) = v*sc + sh
__global__ void bn_finalize(const float* __restrict__ stats, const float* __restrict__ g,
                            const float* __restrict__ be, float* __restrict__ scsh,
                            float inv_n) {
  int t = threadIdx.x;  // 64
  float mean = stats[t] * inv_n;
  float var = stats[64 + t] * inv_n - mean * mean;
  float sc = rsqrtf(var + 1e-5f) * g[t];
  scsh[t] = sc;
  scsh[64 + t] = be[t] - mean * sc;
}

// ---------------- GAT projection: LDS-tiled GEMM, 64 nodes x 128 cols -------
// h = act @ W (BN+ReLU fused into A-staging when BN=true).
template <int K, bool BN>
__global__ __launch_bounds__(256) void gat_project_tiled(
    const float* __restrict__ act, const float* __restrict__ scsh,
    const float* __restrict__ W,
    const float* __restrict__ att_s, const float* __restrict__ att_d,
    __half2* __restrict__ hb, float* __restrict__ as_,
    float* __restrict__ ad_, int n) {
  constexpr int AST = K + 4;
  __shared__ float aS[64 * AST];
  __shared__ float wS[K * 128];
  __shared__ float attS[256];

  int t = threadIdx.x;
  int node0 = blockIdx.x * 64;
  int rows = min(64, n - node0);

  constexpr int AF4 = 64 * K / 4;
  for (int i = t; i < AF4; i += 256) {
    int r = i / (K / 4), kc = i % (K / 4);
    float4 v = make_float4(0.f, 0.f, 0.f, 0.f);
    if (r < rows) v = *(const float4*)&act[(size_t)(node0 + r) * K + kc * 4];
    if (BN) {
      float4 sc4 = *(const float4*)&scsh[kc * 4];
      float4 sh4 = *(const float4*)&scsh[64 + kc * 4];
      v.x = fmaxf(fmaf(v.x, sc4.x, sh4.x), 0.f);
      v.y = fmaxf(fmaf(v.y, sc4.y, sh4.y), 0.f);
      v.z = fmaxf(fmaf(v.z, sc4.z, sh4.z), 0.f);
      v.w = fmaxf(fmaf(v.w, sc4.w, sh4.w), 0.f);
    }
    *(float4*)&aS[r * AST + kc * 4] = v;
  }
  constexpr int WF4 = K * 32;
  for (int i = t; i < WF4; i += 256)
    *(float4*)&wS[i * 4] = *(const float4*)&W[i * 4];
  attS[t] = (t < 128) ? att_s[t] : att_d[t - 128];
  __syncthreads();

  int tc = t & 15, tr = t >> 4;
  int c0 = tc * 8, r0 = tr * 4;

  float acc[4][8] = {};
  for (int k = 0; k < K; k += 4) {
    float4 av[4];
    float4 wv[4][2];
#pragma unroll
    for (int i = 0; i < 4; i++) av[i] = *(const float4*)&aS[(r0 + i) * AST + k];
#pragma unroll
    for (int kk = 0; kk < 4; kk++) {
      wv[kk][0] = *(const float4*)&wS[(k + kk) * 128 + c0];
      wv[kk][1] = *(const float4*)&wS[(k + kk) * 128 + c0 + 4];
    }
#pragma unroll
    for (int i = 0; i < 4; i++) {
      const float* ai = (const float*)&av[i];
#pragma unroll
      for (int kk = 0; kk < 4; kk++) {
        const float* w0 = (const float*)&wv[kk][0];
        const float* w1 = (const float*)&wv[kk][1];
#pragma unroll
        for (int j = 0; j < 4; j++) {
          acc[i][j] = fmaf(ai[kk], w0[j], acc[i][j]);
          acc[i][4 + j] = fmaf(ai[kk], w1[j], acc[i][4 + j]);
        }
      }
    }
  }

#pragma unroll
  for (int i = 0; i < 4; i++) {
    int r = r0 + i;
    float psv = 0.f, pdv = 0.f;
#pragma unroll
    for (int j = 0; j < 8; j++) {
      psv = fmaf(acc[i][j], attS[c0 + j], psv);
      pdv = fmaf(acc[i][j], attS[128 + c0 + j], pdv);
    }
    psv += __shfl_xor(psv, 1); pdv += __shfl_xor(pdv, 1);
    psv += __shfl_xor(psv, 2); pdv += __shfl_xor(pdv, 2);
    psv += __shfl_xor(psv, 4); pdv += __shfl_xor(pdv, 4);
    if (r < rows) {
      size_t base = (size_t)(node0 + r) * 64 + (c0 >> 1);
      hb[base + 0] = __floats2half2_rn(acc[i][0], acc[i][1]);
      hb[base + 1] = __floats2half2_rn(acc[i][2], acc[i][3]);
      hb[base + 2] = __floats2half2_rn(acc[i][4], acc[i][5]);
      hb[base + 3] = __floats2half2_rn(acc[i][6], acc[i][7]);
      if (tc == 0 || tc == 8) {
        int head = tc >> 3;
        as_[(node0 + r) * 2 + head] = psv;
        ad_[(node0 + r) * 2 + head] = pdv;
      }
    }
  }
}

// ---------------- GAT aggregation: wave per node, 8 edges / iteration -------
// sub = lane>>3 picks edge k+sub; q = lane&7 covers flat cols 16q..16q+15
// (q<4 -> head 0, q>=4 -> head 1). Self-loop seeded by sub 0 only; butterfly
// combine over lane^8, lane^16, lane^32.
__device__ __forceinline__ void fma16(float* a, float my, uint4 r0, uint4 r1) {
  float2 f;
  f = __half22float2(__builtin_bit_cast(__half2, r0.x)); a[0] = fmaf(my, f.x, a[0]);  a[1] = fmaf(my, f.y, a[1]);
  f = __half22float2(__builtin_bit_cast(__half2, r0.y)); a[2] = fmaf(my, f.x, a[2]);  a[3] = fmaf(my, f.y, a[3]);
  f = __half22float2(__builtin_bit_cast(__half2, r0.z)); a[4] = fmaf(my, f.x, a[4]);  a[5] = fmaf(my, f.y, a[5]);
  f = __half22float2(__builtin_bit_cast(__half2, r0.w)); a[6] = fmaf(my, f.x, a[6]);  a[7] = fmaf(my, f.y, a[7]);
  f = __half22float2(__builtin_bit_cast(__half2, r1.x)); a[8] = fmaf(my, f.x, a[8]);  a[9] = fmaf(my, f.y, a[9]);
  f = __half22float2(__builtin_bit_cast(__half2, r1.y)); a[10] = fmaf(my, f.x, a[10]); a[11] = fmaf(my, f.y, a[11]);
  f = __half22float2(__builtin_bit_cast(__half2, r1.z)); a[12] = fmaf(my, f.x, a[12]); a[13] = fmaf(my, f.y, a[13]);
  f = __half22float2(__builtin_bit_cast(__half2, r1.w)); a[14] = fmaf(my, f.x, a[14]); a[15] = fmaf(my, f.y, a[15]);
}

__global__ __launch_bounds__(256) void gat_aggregate(
    const __half2* __restrict__ hb, const float2* __restrict__ ee,
    const float* __restrict__ as_, const float* __restrict__ ad_,
    const int* __restrict__ row_ptr, const int2* __restrict__ col2,
    const float* __restrict__ bias, float* __restrict__ out, int n) {
  int wave = (int)((blockIdx.x * blockDim.x + threadIdx.x) >> 6);
  int lane = threadIdx.x & 63;
  if (wave >= n) return;
  int d = wave;
  int sub = lane >> 3, q = lane & 7;
  bool head1 = (q >= 4);
  int beg = row_ptr[d], end = row_ptr[d + 1];
  const uint4* hb4 = (const uint4*)hb;   // 16 uint4 per node (256 B)

  float a[16];
#pragma unroll
  for (int i = 0; i < 16; i++) a[i] = 0.f;
  float dpart = 0.f;

  if (sub == 0) {  // self-loop (not in CSR)
    float2 av = *(const float2*)&as_[d * 2];
    float2 dv = *(const float2*)&ad_[d * 2];
    float e0 = __expf(leaky(av.x + dv.x));
    float e1 = __expf(leaky(av.y + dv.y));
    float my = head1 ? e1 : e0;
    uint4 r0 = hb4[(size_t)d * 16 + q * 2];
    uint4 r1 = hb4[(size_t)d * 16 + q * 2 + 1];
    fma16(a, my, r0, r1);
    dpart = my;
  }

  int k = beg;
  for (; k + 7 < end; k += 8) {
    int kk = k + sub;
    int s = col2[kk].x;
    float2 eev = ee[kk];
    float my = head1 ? eev.y : eev.x;
    uint4 r0 = hb4[(size_t)s * 16 + q * 2];
    uint4 r1 = hb4[(size_t)s * 16 + q * 2 + 1];
    fma16(a, my, r0, r1);
    dpart += my;
  }
  int rem = end - k;
  if (sub < rem) {
    int kk = k + sub;
    int s = col2[kk].x;
    float2 eev = ee[kk];
    float my = head1 ? eev.y : eev.x;
    uint4 r0 = hb4[(size_t)s * 16 + q * 2];
    uint4 r1 = hb4[(size_t)s * 16 + q * 2 + 1];
    fma16(a, my, r0, r1);
    dpart += my;
  }

  // butterfly combine across the 8 sub groups (q preserved)
#pragma unroll
  for (int m = 8; m <= 32; m <<= 1) {
#pragma unroll
    for (int i = 0; i < 16; i++) a[i] += __shfl(a[i], lane ^ m);
    dpart += __shfl(dpart, lane ^ m);
  }
  float dsum = dpart;  // per-head denominator (all subs combined)

  // head-1 values for lane q (<4) live at lane q+4
  int srcl = (lane + 4) & 63;
  float b[16];
#pragma unroll
  for (int i = 0; i < 16; i++) b[i] = __shfl(a[i], srcl);
  float den1 = __shfl(dsum, srcl);
  if (lane < 4) {  // channels 16q..16q+15
    float r0 = 1.f / (dsum + 1e-16f), r1v = 1.f / (den1 + 1e-16f);
#pragma unroll
    for (int j = 0; j < 4; j++) {
      float4 bi = *(const float4*)&bias[lane * 16 + j * 4];
      float4 o;
      o.x = 0.5f * (a[j * 4 + 0] * r0 + b[j * 4 + 0] * r1v) + bi.x;
      o.y = 0.5f * (a[j * 4 + 1] * r0 + b[j * 4 + 1] * r1v) + bi.y;
      o.z = 0.5f * (a[j * 4 + 2] * r0 + b[j * 4 + 2] * r1v) + bi.z;
      o.w = 0.5f * (a[j * 4 + 3] * r0 + b[j * 4 + 3] * r1v) + bi.w;
      *(float4*)&out[(size_t)d * 64 + lane * 16 + j * 4] = o;
    }
  }
}

// ---------------- MLP head: fused tiled GEMM (64 nodes / block) --------------
// a1 staging applies BN(layer3 scsh)+ReLU to the raw aggregate output.
__global__ __launch_bounds__(256) void mlp_head_tiled(
    const float* __restrict__ h3raw, const float* __restrict__ scsh,
    const float* __restrict__ x,
    const float* __restrict__ mW1, const float* __restrict__ mb1,
    const float* __restrict__ mW2, const float* __restrict__ mb2,
    const float* __restrict__ pW, const float* __restrict__ pb,
    const float* __restrict__ vW, const float* __restrict__ vb,
    float* __restrict__ out, int n) {
  __shared__ float lds[13632];
  float* a1  = lds;           // 64*68 = 4352
  float* ctx = lds + 4352;    // 64*8  = 512
  float* a2  = lds + 4864;    // 64*68 = 4352
  float* w1  = lds + 9216;    // 69*64 = 4416
  float* w2  = lds;           // aliases a1 (dead after GEMM1)

  int t = threadIdx.x;
  int node0 = blockIdx.x * 64;
  int rows = min(64, n - node0);

#pragma unroll
  for (int i = 0; i < 4; i++) {
    int flat = t + i * 256;
    int r = flat >> 4, kc = flat & 15;
    float4 v = make_float4(0.f, 0.f, 0.f, 0.f);
    if (r < rows) v = *(const float4*)&h3raw[(size_t)(node0 + r) * 64 + kc * 4];
    float4 sc4 = *(const float4*)&scsh[kc * 4];
    float4 sh4 = *(const float4*)&scsh[64 + kc * 4];
    v.x = fmaxf(fmaf(v.x, sc4.x, sh4.x), 0.f);
    v.y = fmaxf(fmaf(v.y, sc4.y, sh4.y), 0.f);
    v.z = fmaxf(fmaf(v.z, sc4.z, sh4.z), 0.f);
    v.w = fmaxf(fmaf(v.w, sc4.w, sh4.w), 0.f);
    *(float4*)&a1[r * 68 + kc * 4] = v;
  }
  for (int i = t; i < 320; i += 256) {
    int r = i / 5, j = i % 5;
    ctx[r * 8 + j] = (r < rows) ? x[(size_t)(node0 + r) * 16 + 9 + j] : 0.f;
  }
#pragma unroll
  for (int i = 0; i < 5; i++) {
    int flat = t + i * 256;
    if (flat < 1104) *(float4*)&w1[flat * 4] = *(const float4*)&mW1[flat * 4];
  }
  __syncthreads();

  int tc = t & 15, tr = t >> 4;
  int c0 = tc * 4, r0 = tr * 4;

  float acc[4][4] = {};
  for (int k = 0; k < 64; k += 4) {
    float4 av[4], wv[4];
#pragma unroll
    for (int i = 0; i < 4; i++) av[i] = *(const float4*)&a1[(r0 + i) * 68 + k];
#pragma unroll
    for (int j = 0; j < 4; j++) wv[j] = *(const float4*)&w1[(k + j) * 64 + c0];
#pragma unroll
    for (int i = 0; i < 4; i++) {
      const float* ai = (const float*)&av[i];
#pragma unroll
      for (int kk = 0; kk < 4; kk++) {
        const float* wr = (const float*)&wv[kk];
        acc[i][0] = fmaf(ai[kk], wr[0], acc[i][0]);
        acc[i][1] = fmaf(ai[kk], wr[1], acc[i][1]);
        acc[i][2] = fmaf(ai[kk], wr[2], acc[i][2]);
        acc[i][3] = fmaf(ai[kk], wr[3], acc[i][3]);
      }
    }
  }
#pragma unroll
  for (int k = 64; k < 69; k++) {
    float4 wv = *(const float4*)&w1[k * 64 + c0];
    const float* wr = (const float*)&wv;
#pragma unroll
    for (int i = 0; i < 4; i++) {
      float a = ctx[(r0 + i) * 8 + (k - 64)];
      acc[i][0] = fmaf(a, wr[0], acc[i][0]);
      acc[i][1] = fmaf(a, wr[1], acc[i][1]);
      acc[i][2] = fmaf(a, wr[2], acc[i][2]);
      acc[i][3] = fmaf(a, wr[3], acc[i][3]);
    }
  }
  float b1v0 = mb1[c0], b1v1 = mb1[c0 + 1], b1v2 = mb1[c0 + 2], b1v3 = mb1[c0 + 3];
#pragma unroll
  for (int i = 0; i < 4; i++) {
    float4 t1;
    t1.x = fmaxf(acc[i][0] + b1v0, 0.f);
    t1.y = fmaxf(acc[i][1] + b1v1, 0.f);
    t1.z = fmaxf(acc[i][2] + b1v2, 0.f);
    t1.w = fmaxf(acc[i][3] + b1v3, 0.f);
    *(float4*)&a2[(r0 + i) * 68 + c0] = t1;
  }
  __syncthreads();

#pragma unroll
  for (int i = 0; i < 4; i++) {
    int flat = t + i * 256;
    *(float4*)&w2[flat * 4] = *(const float4*)&mW2[flat * 4];
  }
  __syncthreads();

  float acc2[4][4] = {};
  for (int k = 0; k < 64; k += 4) {
    float4 av[4], wv[4];
#pragma unroll
    for (int i = 0; i < 4; i++) av[i] = *(const float4*)&a2[(r0 + i) * 68 + k];
#pragma unroll
    for (int j = 0; j < 4; j++) wv[j] = *(const float4*)&w2[(k + j) * 64 + c0];
#pragma unroll
    for (int i = 0; i < 4; i++) {
      const float* ai = (const float*)&av[i];
#pragma unroll
      for (int kk = 0; kk < 4; kk++) {
        const float* wr = (const float*)&wv[kk];
        acc2[i][0] = fmaf(ai[kk], wr[0], acc2[i][0]);
        acc2[i][1] = fmaf(ai[kk], wr[1], acc2[i][1]);
        acc2[i][2] = fmaf(ai[kk], wr[2], acc2[i][2]);
        acc2[i][3] = fmaf(ai[kk], wr[3], acc2[i][3]);
      }
    }
  }

  float b2v[4], pwv[4], vwv[4];
#pragma unroll
  for (int j = 0; j < 4; j++) {
    b2v[j] = mb2[c0 + j];
    pwv[j] = pW[c0 + j];
    vwv[j] = vW[c0 + j];
  }
  float p[4], v[4];
#pragma unroll
  for (int i = 0; i < 4; i++) {
    float ps = 0.f, vs = 0.f;
#pragma unroll
    for (int j = 0; j < 4; j++) {
      float u = acc2[i][j] + b2v[j];
      ps = fmaf(u, pwv[j], ps);
      vs = fmaf(u, vwv[j], vs);
    }
    p[i] = ps; v[i] = vs;
  }
#pragma unroll
  for (int off = 1; off < 16; off <<= 1) {
#pragma unroll
    for (int i = 0; i < 4; i++) {
      p[i] += __shfl_xor(p[i], off);
      v[i] += __shfl_xor(v[i], off);
    }
  }
  if (tc == 0) {
    float pbs = pb[0], vbs = vb[0];
#pragma unroll
    for (int i = 0; i < 4; i++) {
      int r = r0 + i;
      if (r < rows) {
        out[node0 + r] = p[i] + pbs;
        out[n + node0 + r] = v[i] + vbs;
      }
    }
  }
}

extern "C" void kernel_launch(void* const* d_in, const int* in_sizes, int n_in,
                              void* d_out, int out_size, void* d_ws, size_t ws_size,
                              hipStream_t stream) {
  const float* x = (const float*)d_in[0];
  const int* ei = (const int*)d_in[1];
  const float* W[3]  = {(const float*)d_in[2],  (const float*)d_in[8],  (const float*)d_in[14]};
  const float* AS[3] = {(const float*)d_in[3],  (const float*)d_in[9],  (const float*)d_in[15]};
  const float* AD[3] = {(const float*)d_in[4],  (const float*)d_in[10], (const float*)d_in[16]};
  const float* B[3]  = {(const float*)d_in[5],  (const float*)d_in[11], (const float*)d_in[17]};
  const float* G[3]  = {(const float*)d_in[6],  (const float*)d_in[12], (const float*)d_in[18]};
  const float* BE[3] = {(const float*)d_in[7],  (const float*)d_in[13], (const float*)d_in[19]};
  const float* mW1 = (const float*)d_in[20];
  const float* mb1 = (const float*)d_in[21];
  const float* mW2 = (const float*)d_in[22];
  const float* mb2 = (const float*)d_in[23];
  const float* pW  = (const float*)d_in[24];
  const float* pb  = (const float*)d_in[25];
  const float* vW  = (const float*)d_in[26];
  const float* vb  = (const float*)d_in[27];

  const int N = in_sizes[0] / 16;
  const int E = in_sizes[1] / 2;
  const int* srcp = ei;
  const int* dstp = ei + E;

  // workspace carve-up (~78 MB)
  float* bufB  = (float*)d_ws;               // N*64  raw aggregate output
  float* hbuf  = bufB + (size_t)N * 64;      // N*64 half2 region (N*64 f32 bytes)
  float* as_   = hbuf + (size_t)N * 64;      // N*2
  float* ad_   = as_ + (size_t)N * 2;        // N*2
  float* stats = ad_ + (size_t)N * 2;        // 128
  float* scsh  = stats + 128;                // 128
  int* row_ptr = (int*)(scsh + 128);         // N+1
  int* bcnt    = row_ptr + (N + 1);          // 512
  int* boff    = bcnt + 512;                 // 512
  int* bcur    = boff + 512;                 // 512
  int2* col2   = (int2*)(bcur + 512);        // E int2 (sorted CSR)
  int2* ebuf   = col2 + E;                   // E int2 (staging)
  float2* eeb  = (float2*)(ebuf + E);        // E float2
  __half2* hb  = (__half2*)hbuf;

  const int nbk = (N + 255) >> 8;
  const float inv_n = 1.0f / (float)N;

  // ---- CSR build: binned counting sort
  hipMemsetAsync(bcnt, 0, sizeof(int) * 512, stream);
  bucket_hist<<<256, 256, 0, stream>>>(dstp, bcnt, E);
  bucket_scan<<<1, 512, 0, stream>>>(bcnt, boff, bcur, nbk);
  bin_scatter<<<(E + 8191) / 8192, 256, 0, stream>>>(srcp, dstp, bcur, ebuf, E);
  bucket_sort<<<nbk, 256, 0, stream>>>(ebuf, boff, col2, row_ptr, E, N, nbk);

  const int tiles = (N + 63) / 64;

  // ---- 3 GAT layers (BN+ReLU fused into the next consumer via scsh)
  for (int l = 0; l < 3; l++) {
    if (l == 0)
      gat_project_tiled<16, false><<<tiles, 256, 0, stream>>>(x, scsh, W[l], AS[l], AD[l],
                                                              hb, as_, ad_, N);
    else
      gat_project_tiled<64, true><<<tiles, 256, 0, stream>>>(bufB, scsh, W[l], AS[l], AD[l],
                                                             hb, as_, ad_, N);
    edge_scores<<<(E + 255) / 256, 256, 0, stream>>>(col2, as_, ad_, eeb, E);
    gat_aggregate<<<(N + 3) / 4, 256, 0, stream>>>(hb, eeb, as_, ad_, row_ptr, col2,
                                                   B[l], bufB, N);
    hipMemsetAsync(stats, 0, sizeof(float) * 128, stream);
    bn_stats<<<1024, 256, 0, stream>>>(bufB, stats, N);
    bn_finalize<<<1, 64, 0, stream>>>(stats, G[l], BE[l], scsh, inv_n);
  }

  // ---- MLP head -> (logits, value); applies layer-3 BN+ReLU to bufB
  mlp_head_tiled<<<tiles, 256, 0, stream>>>(bufB, scsh, x, mW1, mb1, mW2, mb2,
                                            pW, pb, vW, vb, (float*)d_out, N);
}

// Round 13
// 596.067 us; speedup vs baseline: 1.0827x; 1.0827x over previous
//
#include <hip/hip_runtime.h>
#include <hip/hip_fp16.h>

// N=100000 nodes, E=1000000 edges, D_IN=16, H=2, C=64.
// 3x (GAT -> BN -> ReLU), then MLP head -> (logits, value) concat in d_out.
// hbuf fp16; edge scores precomputed edge-parallel; aggregation walks
// 4 edges per wave-iteration (16 lanes/edge, 8 ch/lane — R11 sweet spot).
// BN apply fused into consumers via scsh[128]. CSR via binned counting sort.

__device__ __forceinline__ float leaky(float x) { return x > 0.f ? x : 0.2f * x; }

#define BCAP 4096  // max edges per 256-dst bucket (mean ~2560)

// ---------------- CSR build ----------------
__global__ void bucket_hist(const int* __restrict__ dst, int* __restrict__ bcnt, int E) {
  __shared__ int cnt[512];
  int t = threadIdx.x;
  cnt[t] = 0; cnt[t + 256] = 0;
  __syncthreads();
  for (int e = blockIdx.x * blockDim.x + t; e < E; e += gridDim.x * blockDim.x)
    atomicAdd(&cnt[dst[e] >> 8], 1);
  __syncthreads();
  for (int i = t; i < 512; i += 256)
    if (cnt[i]) atomicAdd(&bcnt[i], cnt[i]);
}

__global__ void bucket_scan(const int* __restrict__ bcnt, int* __restrict__ boff,
                            int* __restrict__ bcur, int nbk) {
  __shared__ int temp[512];
  int t = threadIdx.x;  // 512 threads
  int v = (t < nbk) ? bcnt[t] : 0;
  temp[t] = v;
  __syncthreads();
  for (int off = 1; off < 512; off <<= 1) {
    int add = (t >= off) ? temp[t - off] : 0;
    __syncthreads();
    temp[t] += add;
    __syncthreads();
  }
  if (t < nbk) {
    int ex = temp[t] - v;
    boff[t] = ex;
    bcur[t] = ex;
  }
}

__global__ __launch_bounds__(256) void bin_scatter(
    const int* __restrict__ src, const int* __restrict__ dst,
    int* __restrict__ bcur, int2* __restrict__ ebuf, int E) {
  __shared__ int cnt[512];
  __shared__ int base[512];
  int t = threadIdx.x;
  int beg = blockIdx.x * 8192;
  int end = min(E, beg + 8192);
  cnt[t] = 0; cnt[t + 256] = 0;
  __syncthreads();
  for (int e = beg + t; e < end; e += 256)
    atomicAdd(&cnt[dst[e] >> 8], 1);
  __syncthreads();
  for (int i = t; i < 512; i += 256) {
    base[i] = cnt[i] ? atomicAdd(&bcur[i], cnt[i]) : 0;
    cnt[i] = 0;  // reuse as within-run cursor
  }
  __syncthreads();
  for (int e = beg + t; e < end; e += 256) {
    int d = dst[e];
    int bk = d >> 8;
    int off = atomicAdd(&cnt[bk], 1);
    ebuf[base[bk] + off] = make_int2(src[e], d);
  }
}

__global__ __launch_bounds__(256) void bucket_sort(
    const int2* __restrict__ ebuf, const int* __restrict__ boff,
    int2* __restrict__ col2, int* __restrict__ row_ptr, int E, int n, int nbk) {
  __shared__ int2 eds[BCAP];
  __shared__ int dcnt[256];
  __shared__ int dbase[256];
  __shared__ int dexcl[256];
  int b = blockIdx.x, t = threadIdx.x;
  int S = boff[b];
  int Eend = (b + 1 < nbk) ? boff[b + 1] : E;
  int cnt = min(Eend - S, BCAP);
  for (int i = t; i < cnt; i += 256) eds[i] = ebuf[S + i];
  dcnt[t] = 0;
  __syncthreads();
  for (int i = t; i < cnt; i += 256) atomicAdd(&dcnt[eds[i].y & 255], 1);
  __syncthreads();
  int v = dcnt[t];
  dbase[t] = v;
  __syncthreads();
  for (int off = 1; off < 256; off <<= 1) {
    int add = (t >= off) ? dbase[t - off] : 0;
    __syncthreads();
    dbase[t] += add;
    __syncthreads();
  }
  int excl = dbase[t] - v;
  int d = (b << 8) + t;
  if (d < n) row_ptr[d] = S + excl;
  if (b == nbk - 1 && t == 0) row_ptr[n] = E;
  dcnt[t] = 0;  // reuse as per-dst cursor
  dexcl[t] = excl;
  __syncthreads();
  for (int i = t; i < cnt; i += 256) {
    int2 e = eds[i];
    int dl = e.y & 255;
    int off = atomicAdd(&dcnt[dl], 1);
    col2[S + dexcl[dl] + off] = e;
  }
}

// ---------------- edge-parallel softmax numerators -------------------------
__global__ void edge_scores(const int2* __restrict__ col2,
                            const float* __restrict__ as_, const float* __restrict__ ad_,
                            float2* __restrict__ ee, int M) {
  int p = blockIdx.x * blockDim.x + threadIdx.x;
  if (p >= M) return;
  int2 sd = col2[p];
  float2 a = *(const float2*)&as_[sd.x * 2];
  float2 b = *(const float2*)&ad_[sd.y * 2];
  float2 r;
  r.x = __expf(leaky(a.x + b.x));
  r.y = __expf(leaky(a.y + b.y));
  ee[p] = r;
}

// ---------------- BN stats + finalize ----------------
__global__ void bn_stats(const float* __restrict__ h, float* __restrict__ stats, int n) {
  __shared__ float ssum[64], ssq[64];
  int t = threadIdx.x;
  if (t < 64) { ssum[t] = 0.f; ssq[t] = 0.f; }
  __syncthreads();
  int c = t & 63;
  float lsum = 0.f, lsq = 0.f;
  size_t total = (size_t)n * 64;
  for (size_t i = (size_t)blockIdx.x * blockDim.x + t; i < total;
       i += (size_t)gridDim.x * blockDim.x) {
    float v = h[i];
    lsum += v;
    lsq = fmaf(v, v, lsq);
  }
  atomicAdd(&ssum[c], lsum);
  atomicAdd(&ssq[c], lsq);
  __syncthreads();
  if (t < 64) {
    atomicAdd(&stats[t], ssum[t]);
    atomicAdd(&stats[64 + t], ssq[t]);
  }
}

// scsh[c] = scale, scsh[64+c] = shift so that bn(v) = v*sc + sh
__global__ void bn_finalize(const float* __restrict__ stats, const float* __restrict__ g,
                            const float* __restrict__ be, float* __restrict__ scsh,
                            float inv_n) {
  int t = threadIdx.x;  // 64
  float mean = stats[t] * inv_n;
  float var = stats[64 + t] * inv_n - mean * mean;
  float sc = rsqrtf(var + 1e-5f) * g[t];
  scsh[t] = sc;
  scsh[64 + t] = be[t] - mean * sc;
}

// ---------------- GAT projection: LDS-tiled GEMM, 64 nodes x 128 cols -------
// h = act @ W (BN+ReLU fused into A-staging when BN=true).
template <int K, bool BN>
__global__ __launch_bounds__(256) void gat_project_tiled(
    const float* __restrict__ act, const float* __restrict__ scsh,
    const float* __restrict__ W,
    const float* __restrict__ att_s, const float* __restrict__ att_d,
    __half2* __restrict__ hb, float* __restrict__ as_,
    float* __restrict__ ad_, int n) {
  constexpr int AST = K + 4;
  __shared__ float aS[64 * AST];
  __shared__ float wS[K * 128];
  __shared__ float attS[256];

  int t = threadIdx.x;
  int node0 = blockIdx.x * 64;
  int rows = min(64, n - node0);

  constexpr int AF4 = 64 * K / 4;
  for (int i = t; i < AF4; i += 256) {
    int r = i / (K / 4), kc = i % (K / 4);
    float4 v = make_float4(0.f, 0.f, 0.f, 0.f);
    if (r < rows) v = *(const float4*)&act[(size_t)(node0 + r) * K + kc * 4];
    if (BN) {
      float4 sc4 = *(const float4*)&scsh[kc * 4];
      float4 sh4 = *(const float4*)&scsh[64 + kc * 4];
      v.x = fmaxf(fmaf(v.x, sc4.x, sh4.x), 0.f);
      v.y = fmaxf(fmaf(v.y, sc4.y, sh4.y), 0.f);
      v.z = fmaxf(fmaf(v.z, sc4.z, sh4.z), 0.f);
      v.w = fmaxf(fmaf(v.w, sc4.w, sh4.w), 0.f);
    }
    *(float4*)&aS[r * AST + kc * 4] = v;
  }
  constexpr int WF4 = K * 32;
  for (int i = t; i < WF4; i += 256)
    *(float4*)&wS[i * 4] = *(const float4*)&W[i * 4];
  attS[t] = (t < 128) ? att_s[t] : att_d[t - 128];
  __syncthreads();

  int tc = t & 15, tr = t >> 4;
  int c0 = tc * 8, r0 = tr * 4;

  float acc[4][8] = {};
  for (int k = 0; k < K; k += 4) {
    float4 av[4];
    float4 wv[4][2];
#pragma unroll
    for (int i = 0; i < 4; i++) av[i] = *(const float4*)&aS[(r0 + i) * AST + k];
#pragma unroll
    for (int kk = 0; kk < 4; kk++) {
      wv[kk][0] = *(const float4*)&wS[(k + kk) * 128 + c0];
      wv[kk][1] = *(const float4*)&wS[(k + kk) * 128 + c0 + 4];
    }
#pragma unroll
    for (int i = 0; i < 4; i++) {
      const float* ai = (const float*)&av[i];
#pragma unroll
      for (int kk = 0; kk < 4; kk++) {
        const float* w0 = (const float*)&wv[kk][0];
        const float* w1 = (const float*)&wv[kk][1];
#pragma unroll
        for (int j = 0; j < 4; j++) {
          acc[i][j] = fmaf(ai[kk], w0[j], acc[i][j]);
          acc[i][4 + j] = fmaf(ai[kk], w1[j], acc[i][4 + j]);
        }
      }
    }
  }

#pragma unroll
  for (int i = 0; i < 4; i++) {
    int r = r0 + i;
    float psv = 0.f, pdv = 0.f;
#pragma unroll
    for (int j = 0; j < 8; j++) {
      psv = fmaf(acc[i][j], attS[c0 + j], psv);
      pdv = fmaf(acc[i][j], attS[128 + c0 + j], pdv);
    }
    psv += __shfl_xor(psv, 1); pdv += __shfl_xor(pdv, 1);
    psv += __shfl_xor(psv, 2); pdv += __shfl_xor(pdv, 2);
    psv += __shfl_xor(psv, 4); pdv += __shfl_xor(pdv, 4);
    if (r < rows) {
      size_t base = (size_t)(node0 + r) * 64 + (c0 >> 1);
      hb[base + 0] = __floats2half2_rn(acc[i][0], acc[i][1]);
      hb[base + 1] = __floats2half2_rn(acc[i][2], acc[i][3]);
      hb[base + 2] = __floats2half2_rn(acc[i][4], acc[i][5]);
      hb[base + 3] = __floats2half2_rn(acc[i][6], acc[i][7]);
      if (tc == 0 || tc == 8) {
        int head = tc >> 3;
        as_[(node0 + r) * 2 + head] = psv;
        ad_[(node0 + r) * 2 + head] = pdv;
      }
    }
  }
}

// ---------------- GAT aggregation: wave per node, 4 edges / iteration -------
// sub = lane>>4 picks edge k+sub; q = lane&15 covers flat cols 8q..8q+7
// (q<8 -> head 0, q>=8 -> head 1). Self-loop seeded by sub 0 only;
// butterfly combine over lane^16, lane^32. (R11 geometry — measured optimum.)
__global__ __launch_bounds__(256) void gat_aggregate(
    const __half2* __restrict__ hb, const float2* __restrict__ ee,
    const float* __restrict__ as_, const float* __restrict__ ad_,
    const int* __restrict__ row_ptr, const int2* __restrict__ col2,
    const float* __restrict__ bias, float* __restrict__ out, int n) {
  int wave = (int)((blockIdx.x * blockDim.x + threadIdx.x) >> 6);
  int lane = threadIdx.x & 63;
  if (wave >= n) return;
  int d = wave;
  int sub = lane >> 4, q = lane & 15;
  bool head1 = (q >= 8);
  int beg = row_ptr[d], end = row_ptr[d + 1];
  const uint4* hb4 = (const uint4*)hb;   // 16 uint4 per node (256 B)

  float a0 = 0.f, a1 = 0.f, a2 = 0.f, a3 = 0.f;
  float a4 = 0.f, a5 = 0.f, a6 = 0.f, a7 = 0.f;
  float dpart = 0.f;

  if (sub == 0) {  // self-loop (not in CSR)
    float2 av = *(const float2*)&as_[d * 2];
    float2 dv = *(const float2*)&ad_[d * 2];
    float e0 = __expf(leaky(av.x + dv.x));
    float e1 = __expf(leaky(av.y + dv.y));
    float my = head1 ? e1 : e0;
    uint4 raw = hb4[(size_t)d * 16 + q];
    float2 f01 = __half22float2(__builtin_bit_cast(__half2, raw.x));
    float2 f23 = __half22float2(__builtin_bit_cast(__half2, raw.y));
    float2 f45 = __half22float2(__builtin_bit_cast(__half2, raw.z));
    float2 f67 = __half22float2(__builtin_bit_cast(__half2, raw.w));
    a0 = my * f01.x; a1 = my * f01.y; a2 = my * f23.x; a3 = my * f23.y;
    a4 = my * f45.x; a5 = my * f45.y; a6 = my * f67.x; a7 = my * f67.y;
    dpart = my;
  }

  int k = beg;
  for (; k + 3 < end; k += 4) {
    int kk = k + sub;
    int s = col2[kk].x;
    float2 eev = ee[kk];
    float my = head1 ? eev.y : eev.x;
    uint4 raw = hb4[(size_t)s * 16 + q];
    float2 f01 = __half22float2(__builtin_bit_cast(__half2, raw.x));
    float2 f23 = __half22float2(__builtin_bit_cast(__half2, raw.y));
    float2 f45 = __half22float2(__builtin_bit_cast(__half2, raw.z));
    float2 f67 = __half22float2(__builtin_bit_cast(__half2, raw.w));
    a0 = fmaf(my, f01.x, a0); a1 = fmaf(my, f01.y, a1);
    a2 = fmaf(my, f23.x, a2); a3 = fmaf(my, f23.y, a3);
    a4 = fmaf(my, f45.x, a4); a5 = fmaf(my, f45.y, a5);
    a6 = fmaf(my, f67.x, a6); a7 = fmaf(my, f67.y, a7);
    dpart += my;
  }
  int rem = end - k;
  if (sub < rem) {
    int kk = k + sub;
    int s = col2[kk].x;
    float2 eev = ee[kk];
    float my = head1 ? eev.y : eev.x;
    uint4 raw = hb4[(size_t)s * 16 + q];
    float2 f01 = __half22float2(__builtin_bit_cast(__half2, raw.x));
    float2 f23 = __half22float2(__builtin_bit_cast(__half2, raw.y));
    float2 f45 = __half22float2(__builtin_bit_cast(__half2, raw.z));
    float2 f67 = __half22float2(__builtin_bit_cast(__half2, raw.w));
    a0 = fmaf(my, f01.x, a0); a1 = fmaf(my, f01.y, a1);
    a2 = fmaf(my, f23.x, a2); a3 = fmaf(my, f23.y, a3);
    a4 = fmaf(my, f45.x, a4); a5 = fmaf(my, f45.y, a5);
    a6 = fmaf(my, f67.x, a6); a7 = fmaf(my, f67.y, a7);
    dpart += my;
  }

  // butterfly combine across the 4 sub groups (same q)
  a0 += __shfl(a0, lane ^ 16); a1 += __shfl(a1, lane ^ 16);
  a2 += __shfl(a2, lane ^ 16); a3 += __shfl(a3, lane ^ 16);
  a4 += __shfl(a4, lane ^ 16); a5 += __shfl(a5, lane ^ 16);
  a6 += __shfl(a6, lane ^ 16); a7 += __shfl(a7, lane ^ 16);
  dpart += __shfl(dpart, lane ^ 16);
  a0 += __shfl(a0, lane ^ 32); a1 += __shfl(a1, lane ^ 32);
  a2 += __shfl(a2, lane ^ 32); a3 += __shfl(a3, lane ^ 32);
  a4 += __shfl(a4, lane ^ 32); a5 += __shfl(a5, lane ^ 32);
  a6 += __shfl(a6, lane ^ 32); a7 += __shfl(a7, lane ^ 32);
  float dsum = dpart + __shfl(dpart, lane ^ 32);

  // head-1 values for lane q (<8) live at lane q+8 (same sub group)
  int src = (lane + 8) & 63;
  float b0 = __shfl(a0, src), b1 = __shfl(a1, src);
  float b2 = __shfl(a2, src), b3 = __shfl(a3, src);
  float b4 = __shfl(a4, src), b5 = __shfl(a5, src);
  float b6 = __shfl(a6, src), b7 = __shfl(a7, src);
  float den1 = __shfl(dsum, src);
  if (lane < 8) {  // sub 0, q 0..7: output channels 8q..8q+7
    float r0 = 1.f / (dsum + 1e-16f), r1 = 1.f / (den1 + 1e-16f);
    float4 bl = *(const float4*)&bias[q * 8];
    float4 bh = *(const float4*)&bias[q * 8 + 4];
    float4 o0, o1;
    o0.x = 0.5f * (a0 * r0 + b0 * r1) + bl.x;
    o0.y = 0.5f * (a1 * r0 + b1 * r1) + bl.y;
    o0.z = 0.5f * (a2 * r0 + b2 * r1) + bl.z;
    o0.w = 0.5f * (a3 * r0 + b3 * r1) + bl.w;
    o1.x = 0.5f * (a4 * r0 + b4 * r1) + bh.x;
    o1.y = 0.5f * (a5 * r0 + b5 * r1) + bh.y;
    o1.z = 0.5f * (a6 * r0 + b6 * r1) + bh.z;
    o1.w = 0.5f * (a7 * r0 + b7 * r1) + bh.w;
    *(float4*)&out[(size_t)d * 64 + q * 8] = o0;
    *(float4*)&out[(size_t)d * 64 + q * 8 + 4] = o1;
  }
}

// ---------------- MLP head: fused tiled GEMM (64 nodes / block) --------------
// a1 staging applies BN(layer3 scsh)+ReLU to the raw aggregate output.
__global__ __launch_bounds__(256) void mlp_head_tiled(
    const float* __restrict__ h3raw, const float* __restrict__ scsh,
    const float* __restrict__ x,
    const float* __restrict__ mW1, const float* __restrict__ mb1,
    const float* __restrict__ mW2, const float* __restrict__ mb2,
    const float* __restrict__ pW, const float* __restrict__ pb,
    const float* __restrict__ vW, const float* __restrict__ vb,
    float* __restrict__ out, int n) {
  __shared__ float lds[13632];
  float* a1  = lds;           // 64*68 = 4352
  float* ctx = lds + 4352;    // 64*8  = 512
  float* a2  = lds + 4864;    // 64*68 = 4352
  float* w1  = lds + 9216;    // 69*64 = 4416
  float* w2  = lds;           // aliases a1 (dead after GEMM1)

  int t = threadIdx.x;
  int node0 = blockIdx.x * 64;
  int rows = min(64, n - node0);

#pragma unroll
  for (int i = 0; i < 4; i++) {
    int flat = t + i * 256;
    int r = flat >> 4, kc = flat & 15;
    float4 v = make_float4(0.f, 0.f, 0.f, 0.f);
    if (r < rows) v = *(const float4*)&h3raw[(size_t)(node0 + r) * 64 + kc * 4];
    float4 sc4 = *(const float4*)&scsh[kc * 4];
    float4 sh4 = *(const float4*)&scsh[64 + kc * 4];
    v.x = fmaxf(fmaf(v.x, sc4.x, sh4.x), 0.f);
    v.y = fmaxf(fmaf(v.y, sc4.y, sh4.y), 0.f);
    v.z = fmaxf(fmaf(v.z, sc4.z, sh4.z), 0.f);
    v.w = fmaxf(fmaf(v.w, sc4.w, sh4.w), 0.f);
    *(float4*)&a1[r * 68 + kc * 4] = v;
  }
  for (int i = t; i < 320; i += 256) {
    int r = i / 5, j = i % 5;
    ctx[r * 8 + j] = (r < rows) ? x[(size_t)(node0 + r) * 16 + 9 + j] : 0.f;
  }
#pragma unroll
  for (int i = 0; i < 5; i++) {
    int flat = t + i * 256;
    if (flat < 1104) *(float4*)&w1[flat * 4] = *(const float4*)&mW1[flat * 4];
  }
  __syncthreads();

  int tc = t & 15, tr = t >> 4;
  int c0 = tc * 4, r0 = tr * 4;

  float acc[4][4] = {};
  for (int k = 0; k < 64; k += 4) {
    float4 av[4], wv[4];
#pragma unroll
    for (int i = 0; i < 4; i++) av[i] = *(const float4*)&a1[(r0 + i) * 68 + k];
#pragma unroll
    for (int j = 0; j < 4; j++) wv[j] = *(const float4*)&w1[(k + j) * 64 + c0];
#pragma unroll
    for (int i = 0; i < 4; i++) {
      const float* ai = (const float*)&av[i];
#pragma unroll
      for (int kk = 0; kk < 4; kk++) {
        const float* wr = (const float*)&wv[kk];
        acc[i][0] = fmaf(ai[kk], wr[0], acc[i][0]);
        acc[i][1] = fmaf(ai[kk], wr[1], acc[i][1]);
        acc[i][2] = fmaf(ai[kk], wr[2], acc[i][2]);
        acc[i][3] = fmaf(ai[kk], wr[3], acc[i][3]);
      }
    }
  }
#pragma unroll
  for (int k = 64; k < 69; k++) {
    float4 wv = *(const float4*)&w1[k * 64 + c0];
    const float* wr = (const float*)&wv;
#pragma unroll
    for (int i = 0; i < 4; i++) {
      float a = ctx[(r0 + i) * 8 + (k - 64)];
      acc[i][0] = fmaf(a, wr[0], acc[i][0]);
      acc[i][1] = fmaf(a, wr[1], acc[i][1]);
      acc[i][2] = fmaf(a, wr[2], acc[i][2]);
      acc[i][3] = fmaf(a, wr[3], acc[i][3]);
    }
  }
  float b1v0 = mb1[c0], b1v1 = mb1[c0 + 1], b1v2 = mb1[c0 + 2], b1v3 = mb1[c0 + 3];
#pragma unroll
  for (int i = 0; i < 4; i++) {
    float4 t1;
    t1.x = fmaxf(acc[i][0] + b1v0, 0.f);
    t1.y = fmaxf(acc[i][1] + b1v1, 0.f);
    t1.z = fmaxf(acc[i][2] + b1v2, 0.f);
    t1.w = fmaxf(acc[i][3] + b1v3, 0.f);
    *(float4*)&a2[(r0 + i) * 68 + c0] = t1;
  }
  __syncthreads();

#pragma unroll
  for (int i = 0; i < 4; i++) {
    int flat = t + i * 256;
    *(float4*)&w2[flat * 4] = *(const float4*)&mW2[flat * 4];
  }
  __syncthreads();

  float acc2[4][4] = {};
  for (int k = 0; k < 64; k += 4) {
    float4 av[4], wv[4];
#pragma unroll
    for (int i = 0; i < 4; i++) av[i] = *(const float4*)&a2[(r0 + i) * 68 + k];
#pragma unroll
    for (int j = 0; j < 4; j++) wv[j] = *(const float4*)&w2[(k + j) * 64 + c0];
#pragma unroll
    for (int i = 0; i < 4; i++) {
      const float* ai = (const float*)&av[i];
#pragma unroll
      for (int kk = 0; kk < 4; kk++) {
        const float* wr = (const float*)&wv[kk];
        acc2[i][0] = fmaf(ai[kk], wr[0], acc2[i][0]);
        acc2[i][1] = fmaf(ai[kk], wr[1], acc2[i][1]);
        acc2[i][2] = fmaf(ai[kk], wr[2], acc2[i][2]);
        acc2[i][3] = fmaf(ai[kk], wr[3], acc2[i][3]);
      }
    }
  }

  float b2v[4], pwv[4], vwv[4];
#pragma unroll
  for (int j = 0; j < 4; j++) {
    b2v[j] = mb2[c0 + j];
    pwv[j] = pW[c0 + j];
    vwv[j] = vW[c0 + j];
  }
  float p[4], v[4];
#pragma unroll
  for (int i = 0; i < 4; i++) {
    float ps = 0.f, vs = 0.f;
#pragma unroll
    for (int j = 0; j < 4; j++) {
      float u = acc2[i][j] + b2v[j];
      ps = fmaf(u, pwv[j], ps);
      vs = fmaf(u, vwv[j], vs);
    }
    p[i] = ps; v[i] = vs;
  }
#pragma unroll
  for (int off = 1; off < 16; off <<= 1) {
#pragma unroll
    for (int i = 0; i < 4; i++) {
      p[i] += __shfl_xor(p[i], off);
      v[i] += __shfl_xor(v[i], off);
    }
  }
  if (tc == 0) {
    float pbs = pb[0], vbs = vb[0];
#pragma unroll
    for (int i = 0; i < 4; i++) {
      int r = r0 + i;
      if (r < rows) {
        out[node0 + r] = p[i] + pbs;
        out[n + node0 + r] = v[i] + vbs;
      }
    }
  }
}

extern "C" void kernel_launch(void* const* d_in, const int* in_sizes, int n_in,
                              void* d_out, int out_size, void* d_ws, size_t ws_size,
                              hipStream_t stream) {
  const float* x = (const float*)d_in[0];
  const int* ei = (const int*)d_in[1];
  const float* W[3]  = {(const float*)d_in[2],  (const float*)d_in[8],  (const float*)d_in[14]};
  const float* AS[3] = {(const float*)d_in[3],  (const float*)d_in[9],  (const float*)d_in[15]};
  const float* AD[3] = {(const float*)d_in[4],  (const float*)d_in[10], (const float*)d_in[16]};
  const float* B[3]  = {(const float*)d_in[5],  (const float*)d_in[11], (const float*)d_in[17]};
  const float* G[3]  = {(const float*)d_in[6],  (const float*)d_in[12], (const float*)d_in[18]};
  const float* BE[3] = {(const float*)d_in[7],  (const float*)d_in[13], (const float*)d_in[19]};
  const float* mW1 = (const float*)d_in[20];
  const float* mb1 = (const float*)d_in[21];
  const float* mW2 = (const float*)d_in[22];
  const float* mb2 = (const float*)d_in[23];
  const float* pW  = (const float*)d_in[24];
  const float* pb  = (const float*)d_in[25];
  const float* vW  = (const float*)d_in[26];
  const float* vb  = (const float*)d_in[27];

  const int N = in_sizes[0] / 16;
  const int E = in_sizes[1] / 2;
  const int* srcp = ei;
  const int* dstp = ei + E;

  // workspace carve-up (~78 MB)
  float* bufB  = (float*)d_ws;               // N*64  raw aggregate output
  float* hbuf  = bufB + (size_t)N * 64;      // N*64 half2 region (N*64 f32 bytes)
  float* as_   = hbuf + (size_t)N * 64;      // N*2
  float* ad_   = as_ + (size_t)N * 2;        // N*2
  float* stats = ad_ + (size_t)N * 2;        // 128
  float* scsh  = stats + 128;                // 128
  int* row_ptr = (int*)(scsh + 128);         // N+1
  int* bcnt    = row_ptr + (N + 1);          // 512
  int* boff    = bcnt + 512;                 // 512
  int* bcur    = boff + 512;                 // 512
  int2* col2   = (int2*)(bcur + 512);        // E int2 (sorted CSR)
  int2* ebuf   = col2 + E;                   // E int2 (staging)
  float2* eeb  = (float2*)(ebuf + E);        // E float2
  __half2* hb  = (__half2*)hbuf;

  const int nbk = (N + 255) >> 8;
  const float inv_n = 1.0f / (float)N;

  // ---- CSR build: binned counting sort
  hipMemsetAsync(bcnt, 0, sizeof(int) * 512, stream);
  bucket_hist<<<256, 256, 0, stream>>>(dstp, bcnt, E);
  bucket_scan<<<1, 512, 0, stream>>>(bcnt, boff, bcur, nbk);
  bin_scatter<<<(E + 8191) / 8192, 256, 0, stream>>>(srcp, dstp, bcur, ebuf, E);
  bucket_sort<<<nbk, 256, 0, stream>>>(ebuf, boff, col2, row_ptr, E, N, nbk);

  const int tiles = (N + 63) / 64;

  // ---- 3 GAT layers (BN+ReLU fused into the next consumer via scsh)
  for (int l = 0; l < 3; l++) {
    if (l == 0)
      gat_project_tiled<16, false><<<tiles, 256, 0, stream>>>(x, scsh, W[l], AS[l], AD[l],
                                                              hb, as_, ad_, N);
    else
      gat_project_tiled<64, true><<<tiles, 256, 0, stream>>>(bufB, scsh, W[l], AS[l], AD[l],
                                                             hb, as_, ad_, N);
    edge_scores<<<(E + 255) / 256, 256, 0, stream>>>(col2, as_, ad_, eeb, E);
    gat_aggregate<<<(N + 3) / 4, 256, 0, stream>>>(hb, eeb, as_, ad_, row_ptr, col2,
                                                   B[l], bufB, N);
    hipMemsetAsync(stats, 0, sizeof(float) * 128, stream);
    bn_stats<<<1024, 256, 0, stream>>>(bufB, stats, N);
    bn_finalize<<<1, 64, 0, stream>>>(stats, G[l], BE[l], scsh, inv_n);
  }

  // ---- MLP head -> (logits, value); applies layer-3 BN+ReLU to bufB
  mlp_head_tiled<<<tiles, 256, 0, stream>>>(bufB, scsh, x, mW1, mb1, mW2, mb2,
                                            pW, pb, vW, vb, (float*)d_out, N);
}

// Round 14
// 581.230 us; speedup vs baseline: 1.1104x; 1.0255x over previous
//
#include <hip/hip_runtime.h>
#include <hip/hip_fp16.h>

// N=100000 nodes, E=1000000 edges, D_IN=16, H=2, C=64.
// 3x (GAT -> BN -> ReLU), then MLP head -> (logits, value) concat in d_out.
// hbuf fp16; edge scores precomputed; aggregation: 4 edges/group, 16 lanes/edge,
// 2 groups software-pipelined per loop iteration (2 gathers in flight/wave).
// BN apply fused into consumers via scsh[128]. CSR via binned counting sort.

__device__ __forceinline__ float leaky(float x) { return x > 0.f ? x : 0.2f * x; }

#define BCAP 4096  // max edges per 256-dst bucket (mean ~2560)

// ---------------- CSR build ----------------
__global__ void bucket_hist(const int* __restrict__ dst, int* __restrict__ bcnt, int E) {
  __shared__ int cnt[512];
  int t = threadIdx.x;
  cnt[t] = 0; cnt[t + 256] = 0;
  __syncthreads();
  for (int e = blockIdx.x * blockDim.x + t; e < E; e += gridDim.x * blockDim.x)
    atomicAdd(&cnt[dst[e] >> 8], 1);
  __syncthreads();
  for (int i = t; i < 512; i += 256)
    if (cnt[i]) atomicAdd(&bcnt[i], cnt[i]);
}

__global__ void bucket_scan(const int* __restrict__ bcnt, int* __restrict__ boff,
                            int* __restrict__ bcur, int nbk) {
  __shared__ int temp[512];
  int t = threadIdx.x;  // 512 threads
  int v = (t < nbk) ? bcnt[t] : 0;
  temp[t] = v;
  __syncthreads();
  for (int off = 1; off < 512; off <<= 1) {
    int add = (t >= off) ? temp[t - off] : 0;
    __syncthreads();
    temp[t] += add;
    __syncthreads();
  }
  if (t < nbk) {
    int ex = temp[t] - v;
    boff[t] = ex;
    bcur[t] = ex;
  }
}

__global__ __launch_bounds__(256) void bin_scatter(
    const int* __restrict__ src, const int* __restrict__ dst,
    int* __restrict__ bcur, int2* __restrict__ ebuf, int E) {
  __shared__ int cnt[512];
  __shared__ int base[512];
  int t = threadIdx.x;
  int beg = blockIdx.x * 8192;
  int end = min(E, beg + 8192);
  cnt[t] = 0; cnt[t + 256] = 0;
  __syncthreads();
  for (int e = beg + t; e < end; e += 256)
    atomicAdd(&cnt[dst[e] >> 8], 1);
  __syncthreads();
  for (int i = t; i < 512; i += 256) {
    base[i] = cnt[i] ? atomicAdd(&bcur[i], cnt[i]) : 0;
    cnt[i] = 0;  // reuse as within-run cursor
  }
  __syncthreads();
  for (int e = beg + t; e < end; e += 256) {
    int d = dst[e];
    int bk = d >> 8;
    int off = atomicAdd(&cnt[bk], 1);
    ebuf[base[bk] + off] = make_int2(src[e], d);
  }
}

__global__ __launch_bounds__(256) void bucket_sort(
    const int2* __restrict__ ebuf, const int* __restrict__ boff,
    int2* __restrict__ col2, int* __restrict__ row_ptr, int E, int n, int nbk) {
  __shared__ int2 eds[BCAP];
  __shared__ int dcnt[256];
  __shared__ int dbase[256];
  __shared__ int dexcl[256];
  int b = blockIdx.x, t = threadIdx.x;
  int S = boff[b];
  int Eend = (b + 1 < nbk) ? boff[b + 1] : E;
  int cnt = min(Eend - S, BCAP);
  for (int i = t; i < cnt; i += 256) eds[i] = ebuf[S + i];
  dcnt[t] = 0;
  __syncthreads();
  for (int i = t; i < cnt; i += 256) atomicAdd(&dcnt[eds[i].y & 255], 1);
  __syncthreads();
  int v = dcnt[t];
  dbase[t] = v;
  __syncthreads();
  for (int off = 1; off < 256; off <<= 1) {
    int add = (t >= off) ? dbase[t - off] : 0;
    __syncthreads();
    dbase[t] += add;
    __syncthreads();
  }
  int excl = dbase[t] - v;
  int d = (b << 8) + t;
  if (d < n) row_ptr[d] = S + excl;
  if (b == nbk - 1 && t == 0) row_ptr[n] = E;
  dcnt[t] = 0;  // reuse as per-dst cursor
  dexcl[t] = excl;
  __syncthreads();
  for (int i = t; i < cnt; i += 256) {
    int2 e = eds[i];
    int dl = e.y & 255;
    int off = atomicAdd(&dcnt[dl], 1);
    col2[S + dexcl[dl] + off] = e;
  }
}

// ---------------- edge-parallel softmax numerators -------------------------
__global__ void edge_scores(const int2* __restrict__ col2,
                            const float* __restrict__ as_, const float* __restrict__ ad_,
                            float2* __restrict__ ee, int M) {
  int p = blockIdx.x * blockDim.x + threadIdx.x;
  if (p >= M) return;
  int2 sd = col2[p];
  float2 a = *(const float2*)&as_[sd.x * 2];
  float2 b = *(const float2*)&ad_[sd.y * 2];
  float2 r;
  r.x = __expf(leaky(a.x + b.x));
  r.y = __expf(leaky(a.y + b.y));
  ee[p] = r;
}

// ---------------- BN stats + finalize ----------------
__global__ void bn_stats(const float* __restrict__ h, float* __restrict__ stats, int n) {
  __shared__ float ssum[64], ssq[64];
  int t = threadIdx.x;
  if (t < 64) { ssum[t] = 0.f; ssq[t] = 0.f; }
  __syncthreads();
  int c = t & 63;
  float lsum = 0.f, lsq = 0.f;
  size_t total = (size_t)n * 64;
  for (size_t i = (size_t)blockIdx.x * blockDim.x + t; i < total;
       i += (size_t)gridDim.x * blockDim.x) {
    float v = h[i];
    lsum += v;
    lsq = fmaf(v, v, lsq);
  }
  atomicAdd(&ssum[c], lsum);
  atomicAdd(&ssq[c], lsq);
  __syncthreads();
  if (t < 64) {
    atomicAdd(&stats[t], ssum[t]);
    atomicAdd(&stats[64 + t], ssq[t]);
  }
}

// scsh[c] = scale, scsh[64+c] = shift so that bn(v) = v*sc + sh
__global__ void bn_finalize(const float* __restrict__ stats, const float* __restrict__ g,
                            const float* __restrict__ be, float* __restrict__ scsh,
                            float inv_n) {
  int t = threadIdx.x;  // 64
  float mean = stats[t] * inv_n;
  float var = stats[64 + t] * inv_n - mean * mean;
  float sc = rsqrtf(var + 1e-5f) * g[t];
  scsh[t] = sc;
  scsh[64 + t] = be[t] - mean * sc;
}

// ---------------- GAT projection: LDS-tiled GEMM, 64 nodes x 128 cols -------
// h = act @ W (BN+ReLU fused into A-staging when BN=true).
template <int K, bool BN>
__global__ __launch_bounds__(256) void gat_project_tiled(
    const float* __restrict__ act, const float* __restrict__ scsh,
    const float* __restrict__ W,
    const float* __restrict__ att_s, const float* __restrict__ att_d,
    __half2* __restrict__ hb, float* __restrict__ as_,
    float* __restrict__ ad_, int n) {
  constexpr int AST = K + 4;
  __shared__ float aS[64 * AST];
  __shared__ float wS[K * 128];
  __shared__ float attS[256];

  int t = threadIdx.x;
  int node0 = blockIdx.x * 64;
  int rows = min(64, n - node0);

  constexpr int AF4 = 64 * K / 4;
  for (int i = t; i < AF4; i += 256) {
    int r = i / (K / 4), kc = i % (K / 4);
    float4 v = make_float4(0.f, 0.f, 0.f, 0.f);
    if (r < rows) v = *(const float4*)&act[(size_t)(node0 + r) * K + kc * 4];
    if (BN) {
      float4 sc4 = *(const float4*)&scsh[kc * 4];
      float4 sh4 = *(const float4*)&scsh[64 + kc * 4];
      v.x = fmaxf(fmaf(v.x, sc4.x, sh4.x), 0.f);
      v.y = fmaxf(fmaf(v.y, sc4.y, sh4.y), 0.f);
      v.z = fmaxf(fmaf(v.z, sc4.z, sh4.z), 0.f);
      v.w = fmaxf(fmaf(v.w, sc4.w, sh4.w), 0.f);
    }
    *(float4*)&aS[r * AST + kc * 4] = v;
  }
  constexpr int WF4 = K * 32;
  for (int i = t; i < WF4; i += 256)
    *(float4*)&wS[i * 4] = *(const float4*)&W[i * 4];
  attS[t] = (t < 128) ? att_s[t] : att_d[t - 128];
  __syncthreads();

  int tc = t & 15, tr = t >> 4;
  int c0 = tc * 8, r0 = tr * 4;

  float acc[4][8] = {};
  for (int k = 0; k < K; k += 4) {
    float4 av[4];
    float4 wv[4][2];
#pragma unroll
    for (int i = 0; i < 4; i++) av[i] = *(const float4*)&aS[(r0 + i) * AST + k];
#pragma unroll
    for (int kk = 0; kk < 4; kk++) {
      wv[kk][0] = *(const float4*)&wS[(k + kk) * 128 + c0];
      wv[kk][1] = *(const float4*)&wS[(k + kk) * 128 + c0 + 4];
    }
#pragma unroll
    for (int i = 0; i < 4; i++) {
      const float* ai = (const float*)&av[i];
#pragma unroll
      for (int kk = 0; kk < 4; kk++) {
        const float* w0 = (const float*)&wv[kk][0];
        const float* w1 = (const float*)&wv[kk][1];
#pragma unroll
        for (int j = 0; j < 4; j++) {
          acc[i][j] = fmaf(ai[kk], w0[j], acc[i][j]);
          acc[i][4 + j] = fmaf(ai[kk], w1[j], acc[i][4 + j]);
        }
      }
    }
  }

#pragma unroll
  for (int i = 0; i < 4; i++) {
    int r = r0 + i;
    float psv = 0.f, pdv = 0.f;
#pragma unroll
    for (int j = 0; j < 8; j++) {
      psv = fmaf(acc[i][j], attS[c0 + j], psv);
      pdv = fmaf(acc[i][j], attS[128 + c0 + j], pdv);
    }
    psv += __shfl_xor(psv, 1); pdv += __shfl_xor(pdv, 1);
    psv += __shfl_xor(psv, 2); pdv += __shfl_xor(pdv, 2);
    psv += __shfl_xor(psv, 4); pdv += __shfl_xor(pdv, 4);
    if (r < rows) {
      size_t base = (size_t)(node0 + r) * 64 + (c0 >> 1);
      hb[base + 0] = __floats2half2_rn(acc[i][0], acc[i][1]);
      hb[base + 1] = __floats2half2_rn(acc[i][2], acc[i][3]);
      hb[base + 2] = __floats2half2_rn(acc[i][4], acc[i][5]);
      hb[base + 3] = __floats2half2_rn(acc[i][6], acc[i][7]);
      if (tc == 0 || tc == 8) {
        int head = tc >> 3;
        as_[(node0 + r) * 2 + head] = psv;
        ad_[(node0 + r) * 2 + head] = pdv;
      }
    }
  }
}

// ---------------- GAT aggregation: wave per node ----------------------------
// 4 edges/group, 16 lanes/edge (sub = lane>>4, q = lane&15, 8 ch/lane).
// Loop processes TWO groups per iteration with both gathers issued up front
// (software pipeline: 2 outstanding row gathers per wave).
__device__ __forceinline__ void fma8(float* a, float my, uint4 raw) {
  float2 f;
  f = __half22float2(__builtin_bit_cast(__half2, raw.x)); a[0] = fmaf(my, f.x, a[0]); a[1] = fmaf(my, f.y, a[1]);
  f = __half22float2(__builtin_bit_cast(__half2, raw.y)); a[2] = fmaf(my, f.x, a[2]); a[3] = fmaf(my, f.y, a[3]);
  f = __half22float2(__builtin_bit_cast(__half2, raw.z)); a[4] = fmaf(my, f.x, a[4]); a[5] = fmaf(my, f.y, a[5]);
  f = __half22float2(__builtin_bit_cast(__half2, raw.w)); a[6] = fmaf(my, f.x, a[6]); a[7] = fmaf(my, f.y, a[7]);
}

__global__ __launch_bounds__(256) void gat_aggregate(
    const __half2* __restrict__ hb, const float2* __restrict__ ee,
    const float* __restrict__ as_, const float* __restrict__ ad_,
    const int* __restrict__ row_ptr, const int2* __restrict__ col2,
    const float* __restrict__ bias, float* __restrict__ out, int n) {
  int wave = (int)((blockIdx.x * blockDim.x + threadIdx.x) >> 6);
  int lane = threadIdx.x & 63;
  if (wave >= n) return;
  int d = wave;
  int sub = lane >> 4, q = lane & 15;
  bool head1 = (q >= 8);
  int beg = row_ptr[d], end = row_ptr[d + 1];
  const uint4* hb4 = (const uint4*)hb;   // 16 uint4 per node (256 B)

  float a[8] = {};
  float dpart = 0.f;

  if (sub == 0) {  // self-loop (not in CSR)
    float2 av = *(const float2*)&as_[d * 2];
    float2 dv = *(const float2*)&ad_[d * 2];
    float e0 = __expf(leaky(av.x + dv.x));
    float e1 = __expf(leaky(av.y + dv.y));
    float my = head1 ? e1 : e0;
    uint4 raw = hb4[(size_t)d * 16 + q];
    fma8(a, my, raw);
    dpart = my;
  }

  int k = beg;
  // 2 groups of 4 edges per iteration, both gathers issued before the FMAs
  for (; k + 7 < end; k += 8) {
    int kkA = k + sub, kkB = k + 4 + sub;
    int sA = col2[kkA].x;
    int sB = col2[kkB].x;
    float2 eevA = ee[kkA];
    float2 eevB = ee[kkB];
    uint4 rawA = hb4[(size_t)sA * 16 + q];
    uint4 rawB = hb4[(size_t)sB * 16 + q];
    float myA = head1 ? eevA.y : eevA.x;
    float myB = head1 ? eevB.y : eevB.x;
    fma8(a, myA, rawA);
    dpart += myA;
    fma8(a, myB, rawB);
    dpart += myB;
  }
  if (k + 3 < end) {  // one full group of 4
    int kk = k + sub;
    int s = col2[kk].x;
    float2 eev = ee[kk];
    float my = head1 ? eev.y : eev.x;
    uint4 raw = hb4[(size_t)s * 16 + q];
    fma8(a, my, raw);
    dpart += my;
    k += 4;
  }
  int rem = end - k;
  if (sub < rem) {  // remainder 0..3
    int kk = k + sub;
    int s = col2[kk].x;
    float2 eev = ee[kk];
    float my = head1 ? eev.y : eev.x;
    uint4 raw = hb4[(size_t)s * 16 + q];
    fma8(a, my, raw);
    dpart += my;
  }

  // butterfly combine across the 4 sub groups (same q)
#pragma unroll
  for (int i = 0; i < 8; i++) a[i] += __shfl(a[i], lane ^ 16);
  dpart += __shfl(dpart, lane ^ 16);
#pragma unroll
  for (int i = 0; i < 8; i++) a[i] += __shfl(a[i], lane ^ 32);
  float dsum = dpart + __shfl(dpart, lane ^ 32);

  // head-1 values for lane q (<8) live at lane q+8 (same sub group)
  int src = (lane + 8) & 63;
  float b[8];
#pragma unroll
  for (int i = 0; i < 8; i++) b[i] = __shfl(a[i], src);
  float den1 = __shfl(dsum, src);
  if (lane < 8) {  // sub 0, q 0..7: output channels 8q..8q+7
    float r0 = 1.f / (dsum + 1e-16f), r1 = 1.f / (den1 + 1e-16f);
    float4 bl = *(const float4*)&bias[q * 8];
    float4 bh = *(const float4*)&bias[q * 8 + 4];
    float4 o0, o1;
    o0.x = 0.5f * (a[0] * r0 + b[0] * r1) + bl.x;
    o0.y = 0.5f * (a[1] * r0 + b[1] * r1) + bl.y;
    o0.z = 0.5f * (a[2] * r0 + b[2] * r1) + bl.z;
    o0.w = 0.5f * (a[3] * r0 + b[3] * r1) + bl.w;
    o1.x = 0.5f * (a[4] * r0 + b[4] * r1) + bh.x;
    o1.y = 0.5f * (a[5] * r0 + b[5] * r1) + bh.y;
    o1.z = 0.5f * (a[6] * r0 + b[6] * r1) + bh.z;
    o1.w = 0.5f * (a[7] * r0 + b[7] * r1) + bh.w;
    *(float4*)&out[(size_t)d * 64 + q * 8] = o0;
    *(float4*)&out[(size_t)d * 64 + q * 8 + 4] = o1;
  }
}

// ---------------- MLP head: fused tiled GEMM (64 nodes / block) --------------
// a1 staging applies BN(layer3 scsh)+ReLU to the raw aggregate output.
__global__ __launch_bounds__(256) void mlp_head_tiled(
    const float* __restrict__ h3raw, const float* __restrict__ scsh,
    const float* __restrict__ x,
    const float* __restrict__ mW1, const float* __restrict__ mb1,
    const float* __restrict__ mW2, const float* __restrict__ mb2,
    const float* __restrict__ pW, const float* __restrict__ pb,
    const float* __restrict__ vW, const float* __restrict__ vb,
    float* __restrict__ out, int n) {
  __shared__ float lds[13632];
  float* a1  = lds;           // 64*68 = 4352
  float* ctx = lds + 4352;    // 64*8  = 512
  float* a2  = lds + 4864;    // 64*68 = 4352
  float* w1  = lds + 9216;    // 69*64 = 4416
  float* w2  = lds;           // aliases a1 (dead after GEMM1)

  int t = threadIdx.x;
  int node0 = blockIdx.x * 64;
  int rows = min(64, n - node0);

#pragma unroll
  for (int i = 0; i < 4; i++) {
    int flat = t + i * 256;
    int r = flat >> 4, kc = flat & 15;
    float4 v = make_float4(0.f, 0.f, 0.f, 0.f);
    if (r < rows) v = *(const float4*)&h3raw[(size_t)(node0 + r) * 64 + kc * 4];
    float4 sc4 = *(const float4*)&scsh[kc * 4];
    float4 sh4 = *(const float4*)&scsh[64 + kc * 4];
    v.x = fmaxf(fmaf(v.x, sc4.x, sh4.x), 0.f);
    v.y = fmaxf(fmaf(v.y, sc4.y, sh4.y), 0.f);
    v.z = fmaxf(fmaf(v.z, sc4.z, sh4.z), 0.f);
    v.w = fmaxf(fmaf(v.w, sc4.w, sh4.w), 0.f);
    *(float4*)&a1[r * 68 + kc * 4] = v;
  }
  for (int i = t; i < 320; i += 256) {
    int r = i / 5, j = i % 5;
    ctx[r * 8 + j] = (r < rows) ? x[(size_t)(node0 + r) * 16 + 9 + j] : 0.f;
  }
#pragma unroll
  for (int i = 0; i < 5; i++) {
    int flat = t + i * 256;
    if (flat < 1104) *(float4*)&w1[flat * 4] = *(const float4*)&mW1[flat * 4];
  }
  __syncthreads();

  int tc = t & 15, tr = t >> 4;
  int c0 = tc * 4, r0 = tr * 4;

  float acc[4][4] = {};
  for (int k = 0; k < 64; k += 4) {
    float4 av[4], wv[4];
#pragma unroll
    for (int i = 0; i < 4; i++) av[i] = *(const float4*)&a1[(r0 + i) * 68 + k];
#pragma unroll
    for (int j = 0; j < 4; j++) wv[j] = *(const float4*)&w1[(k + j) * 64 + c0];
#pragma unroll
    for (int i = 0; i < 4; i++) {
      const float* ai = (const float*)&av[i];
#pragma unroll
      for (int kk = 0; kk < 4; kk++) {
        const float* wr = (const float*)&wv[kk];
        acc[i][0] = fmaf(ai[kk], wr[0], acc[i][0]);
        acc[i][1] = fmaf(ai[kk], wr[1], acc[i][1]);
        acc[i][2] = fmaf(ai[kk], wr[2], acc[i][2]);
        acc[i][3] = fmaf(ai[kk], wr[3], acc[i][3]);
      }
    }
  }
#pragma unroll
  for (int k = 64; k < 69; k++) {
    float4 wv = *(const float4*)&w1[k * 64 + c0];
    const float* wr = (const float*)&wv;
#pragma unroll
    for (int i = 0; i < 4; i++) {
      float a = ctx[(r0 + i) * 8 + (k - 64)];
      acc[i][0] = fmaf(a, wr[0], acc[i][0]);
      acc[i][1] = fmaf(a, wr[1], acc[i][1]);
      acc[i][2] = fmaf(a, wr[2], acc[i][2]);
      acc[i][3] = fmaf(a, wr[3], acc[i][3]);
    }
  }
  float b1v0 = mb1[c0], b1v1 = mb1[c0 + 1], b1v2 = mb1[c0 + 2], b1v3 = mb1[c0 + 3];
#pragma unroll
  for (int i = 0; i < 4; i++) {
    float4 t1;
    t1.x = fmaxf(acc[i][0] + b1v0, 0.f);
    t1.y = fmaxf(acc[i][1] + b1v1, 0.f);
    t1.z = fmaxf(acc[i][2] + b1v2, 0.f);
    t1.w = fmaxf(acc[i][3] + b1v3, 0.f);
    *(float4*)&a2[(r0 + i) * 68 + c0] = t1;
  }
  __syncthreads();

#pragma unroll
  for (int i = 0; i < 4; i++) {
    int flat = t + i * 256;
    *(float4*)&w2[flat * 4] = *(const float4*)&mW2[flat * 4];
  }
  __syncthreads();

  float acc2[4][4] = {};
  for (int k = 0; k < 64; k += 4) {
    float4 av[4], wv[4];
#pragma unroll
    for (int i = 0; i < 4; i++) av[i] = *(const float4*)&a2[(r0 + i) * 68 + k];
#pragma unroll
    for (int j = 0; j < 4; j++) wv[j] = *(const float4*)&w2[(k + j) * 64 + c0];
#pragma unroll
    for (int i = 0; i < 4; i++) {
      const float* ai = (const float*)&av[i];
#pragma unroll
      for (int kk = 0; kk < 4; kk++) {
        const float* wr = (const float*)&wv[kk];
        acc2[i][0] = fmaf(ai[kk], wr[0], acc2[i][0]);
        acc2[i][1] = fmaf(ai[kk], wr[1], acc2[i][1]);
        acc2[i][2] = fmaf(ai[kk], wr[2], acc2[i][2]);
        acc2[i][3] = fmaf(ai[kk], wr[3], acc2[i][3]);
      }
    }
  }

  float b2v[4], pwv[4], vwv[4];
#pragma unroll
  for (int j = 0; j < 4; j++) {
    b2v[j] = mb2[c0 + j];
    pwv[j] = pW[c0 + j];
    vwv[j] = vW[c0 + j];
  }
  float p[4], v[4];
#pragma unroll
  for (int i = 0; i < 4; i++) {
    float ps = 0.f, vs = 0.f;
#pragma unroll
    for (int j = 0; j < 4; j++) {
      float u = acc2[i][j] + b2v[j];
      ps = fmaf(u, pwv[j], ps);
      vs = fmaf(u, vwv[j], vs);
    }
    p[i] = ps; v[i] = vs;
  }
#pragma unroll
  for (int off = 1; off < 16; off <<= 1) {
#pragma unroll
    for (int i = 0; i < 4; i++) {
      p[i] += __shfl_xor(p[i], off);
      v[i] += __shfl_xor(v[i], off);
    }
  }
  if (tc == 0) {
    float pbs = pb[0], vbs = vb[0];
#pragma unroll
    for (int i = 0; i < 4; i++) {
      int r = r0 + i;
      if (r < rows) {
        out[node0 + r] = p[i] + pbs;
        out[n + node0 + r] = v[i] + vbs;
      }
    }
  }
}

extern "C" void kernel_launch(void* const* d_in, const int* in_sizes, int n_in,
                              void* d_out, int out_size, void* d_ws, size_t ws_size,
                              hipStream_t stream) {
  const float* x = (const float*)d_in[0];
  const int* ei = (const int*)d_in[1];
  const float* W[3]  = {(const float*)d_in[2],  (const float*)d_in[8],  (const float*)d_in[14]};
  const float* AS[3] = {(const float*)d_in[3],  (const float*)d_in[9],  (const float*)d_in[15]};
  const float* AD[3] = {(const float*)d_in[4],  (const float*)d_in[10], (const float*)d_in[16]};
  const float* B[3]  = {(const float*)d_in[5],  (const float*)d_in[11], (const float*)d_in[17]};
  const float* G[3]  = {(const float*)d_in[6],  (const float*)d_in[12], (const float*)d_in[18]};
  const float* BE[3] = {(const float*)d_in[7],  (const float*)d_in[13], (const float*)d_in[19]};
  const float* mW1 = (const float*)d_in[20];
  const float* mb1 = (const float*)d_in[21];
  const float* mW2 = (const float*)d_in[22];
  const float* mb2 = (const float*)d_in[23];
  const float* pW  = (const float*)d_in[24];
  const float* pb  = (const float*)d_in[25];
  const float* vW  = (const float*)d_in[26];
  const float* vb  = (const float*)d_in[27];

  const int N = in_sizes[0] / 16;
  const int E = in_sizes[1] / 2;
  const int* srcp = ei;
  const int* dstp = ei + E;

  // workspace carve-up (~78 MB)
  float* bufB  = (float*)d_ws;               // N*64  raw aggregate output
  float* hbuf  = bufB + (size_t)N * 64;      // N*64 half2 region (N*64 f32 bytes)
  float* as_   = hbuf + (size_t)N * 64;      // N*2
  float* ad_   = as_ + (size_t)N * 2;        // N*2
  float* stats = ad_ + (size_t)N * 2;        // 128
  float* scsh  = stats + 128;                // 128
  int* row_ptr = (int*)(scsh + 128);         // N+1
  int* bcnt    = row_ptr + (N + 1);          // 512
  int* boff    = bcnt + 512;                 // 512
  int* bcur    = boff + 512;                 // 512
  int2* col2   = (int2*)(bcur + 512);        // E int2 (sorted CSR)
  int2* ebuf   = col2 + E;                   // E int2 (staging)
  float2* eeb  = (float2*)(ebuf + E);        // E float2
  __half2* hb  = (__half2*)hbuf;

  const int nbk = (N + 255) >> 8;
  const float inv_n = 1.0f / (float)N;

  // ---- CSR build: binned counting sort
  hipMemsetAsync(bcnt, 0, sizeof(int) * 512, stream);
  bucket_hist<<<256, 256, 0, stream>>>(dstp, bcnt, E);
  bucket_scan<<<1, 512, 0, stream>>>(bcnt, boff, bcur, nbk);
  bin_scatter<<<(E + 8191) / 8192, 256, 0, stream>>>(srcp, dstp, bcur, ebuf, E);
  bucket_sort<<<nbk, 256, 0, stream>>>(ebuf, boff, col2, row_ptr, E, N, nbk);

  const int tiles = (N + 63) / 64;

  // ---- 3 GAT layers (BN+ReLU fused into the next consumer via scsh)
  for (int l = 0; l < 3; l++) {
    if (l == 0)
      gat_project_tiled<16, false><<<tiles, 256, 0, stream>>>(x, scsh, W[l], AS[l], AD[l],
                                                              hb, as_, ad_, N);
    else
      gat_project_tiled<64, true><<<tiles, 256, 0, stream>>>(bufB, scsh, W[l], AS[l], AD[l],
                                                             hb, as_, ad_, N);
    edge_scores<<<(E + 255) / 256, 256, 0, stream>>>(col2, as_, ad_, eeb, E);
    gat_aggregate<<<(N + 3) / 4, 256, 0, stream>>>(hb, eeb, as_, ad_, row_ptr, col2,
                                                   B[l], bufB, N);
    hipMemsetAsync(stats, 0, sizeof(float) * 128, stream);
    bn_stats<<<1024, 256, 0, stream>>>(bufB, stats, N);
    bn_finalize<<<1, 64, 0, stream>>>(stats, G[l], BE[l], scsh, inv_n);
  }

  // ---- MLP head -> (logits, value); applies layer-3 BN+ReLU to bufB
  mlp_head_tiled<<<tiles, 256, 0, stream>>>(bufB, scsh, x, mW1, mb1, mW2, mb2,
                                            pW, pb, vW, vb, (float*)d_out, N);
}

// Round 15
// 570.023 us; speedup vs baseline: 1.1322x; 1.0197x over previous
//
#include <hip/hip_runtime.h>
#include <hip/hip_fp16.h>

// N=100000 nodes, E=1000000 edges, D_IN=16, H=2, C=64.
// 3x (GAT -> BN -> ReLU), then MLP head -> (logits, value) concat in d_out.
// hbuf fp16; aggregation: 4 edges/group, 16 lanes/edge, 2 groups pipelined
// per iteration; edge softmax scores computed INLINE (as_ gather is
// L2-resident; saves the edge_scores pass + ee traffic).
// BN apply fused into consumers via scsh[128]. CSR via binned counting sort.

__device__ __forceinline__ float leaky(float x) { return x > 0.f ? x : 0.2f * x; }

#define BCAP 4096  // max edges per 256-dst bucket (mean ~2560)

// ---------------- CSR build ----------------
__global__ void bucket_hist(const int* __restrict__ dst, int* __restrict__ bcnt, int E) {
  __shared__ int cnt[512];
  int t = threadIdx.x;
  cnt[t] = 0; cnt[t + 256] = 0;
  __syncthreads();
  for (int e = blockIdx.x * blockDim.x + t; e < E; e += gridDim.x * blockDim.x)
    atomicAdd(&cnt[dst[e] >> 8], 1);
  __syncthreads();
  for (int i = t; i < 512; i += 256)
    if (cnt[i]) atomicAdd(&bcnt[i], cnt[i]);
}

__global__ void bucket_scan(const int* __restrict__ bcnt, int* __restrict__ boff,
                            int* __restrict__ bcur, int nbk) {
  __shared__ int temp[512];
  int t = threadIdx.x;  // 512 threads
  int v = (t < nbk) ? bcnt[t] : 0;
  temp[t] = v;
  __syncthreads();
  for (int off = 1; off < 512; off <<= 1) {
    int add = (t >= off) ? temp[t - off] : 0;
    __syncthreads();
    temp[t] += add;
    __syncthreads();
  }
  if (t < nbk) {
    int ex = temp[t] - v;
    boff[t] = ex;
    bcur[t] = ex;
  }
}

__global__ __launch_bounds__(256) void bin_scatter(
    const int* __restrict__ src, const int* __restrict__ dst,
    int* __restrict__ bcur, int2* __restrict__ ebuf, int E) {
  __shared__ int cnt[512];
  __shared__ int base[512];
  int t = threadIdx.x;
  int beg = blockIdx.x * 8192;
  int end = min(E, beg + 8192);
  cnt[t] = 0; cnt[t + 256] = 0;
  __syncthreads();
  for (int e = beg + t; e < end; e += 256)
    atomicAdd(&cnt[dst[e] >> 8], 1);
  __syncthreads();
  for (int i = t; i < 512; i += 256) {
    base[i] = cnt[i] ? atomicAdd(&bcur[i], cnt[i]) : 0;
    cnt[i] = 0;  // reuse as within-run cursor
  }
  __syncthreads();
  for (int e = beg + t; e < end; e += 256) {
    int d = dst[e];
    int bk = d >> 8;
    int off = atomicAdd(&cnt[bk], 1);
    ebuf[base[bk] + off] = make_int2(src[e], d);
  }
}

__global__ __launch_bounds__(256) void bucket_sort(
    const int2* __restrict__ ebuf, const int* __restrict__ boff,
    int2* __restrict__ col2, int* __restrict__ row_ptr, int E, int n, int nbk) {
  __shared__ int2 eds[BCAP];
  __shared__ int dcnt[256];
  __shared__ int dbase[256];
  __shared__ int dexcl[256];
  int b = blockIdx.x, t = threadIdx.x;
  int S = boff[b];
  int Eend = (b + 1 < nbk) ? boff[b + 1] : E;
  int cnt = min(Eend - S, BCAP);
  for (int i = t; i < cnt; i += 256) eds[i] = ebuf[S + i];
  dcnt[t] = 0;
  __syncthreads();
  for (int i = t; i < cnt; i += 256) atomicAdd(&dcnt[eds[i].y & 255], 1);
  __syncthreads();
  int v = dcnt[t];
  dbase[t] = v;
  __syncthreads();
  for (int off = 1; off < 256; off <<= 1) {
    int add = (t >= off) ? dbase[t - off] : 0;
    __syncthreads();
    dbase[t] += add;
    __syncthreads();
  }
  int excl = dbase[t] - v;
  int d = (b << 8) + t;
  if (d < n) row_ptr[d] = S + excl;
  if (b == nbk - 1 && t == 0) row_ptr[n] = E;
  dcnt[t] = 0;  // reuse as per-dst cursor
  dexcl[t] = excl;
  __syncthreads();
  for (int i = t; i < cnt; i += 256) {
    int2 e = eds[i];
    int dl = e.y & 255;
    int off = atomicAdd(&dcnt[dl], 1);
    col2[S + dexcl[dl] + off] = e;
  }
}

// ---------------- BN stats + finalize ----------------
__global__ void bn_stats(const float* __restrict__ h, float* __restrict__ stats, int n) {
  __shared__ float ssum[64], ssq[64];
  int t = threadIdx.x;
  if (t < 64) { ssum[t] = 0.f; ssq[t] = 0.f; }
  __syncthreads();
  int c = t & 63;
  float lsum = 0.f, lsq = 0.f;
  size_t total = (size_t)n * 64;
  for (size_t i = (size_t)blockIdx.x * blockDim.x + t; i < total;
       i += (size_t)gridDim.x * blockDim.x) {
    float v = h[i];
    lsum += v;
    lsq = fmaf(v, v, lsq);
  }
  atomicAdd(&ssum[c], lsum);
  atomicAdd(&ssq[c], lsq);
  __syncthreads();
  if (t < 64) {
    atomicAdd(&stats[t], ssum[t]);
    atomicAdd(&stats[64 + t], ssq[t]);
  }
}

// scsh[c] = scale, scsh[64+c] = shift so that bn(v) = v*sc + sh
__global__ void bn_finalize(const float* __restrict__ stats, const float* __restrict__ g,
                            const float* __restrict__ be, float* __restrict__ scsh,
                            float inv_n) {
  int t = threadIdx.x;  // 64
  float mean = stats[t] * inv_n;
  float var = stats[64 + t] * inv_n - mean * mean;
  float sc = rsqrtf(var + 1e-5f) * g[t];
  scsh[t] = sc;
  scsh[64 + t] = be[t] - mean * sc;
}

// ---------------- GAT projection: LDS-tiled GEMM, 64 nodes x 128 cols -------
// h = act @ W (BN+ReLU fused into A-staging when BN=true).
template <int K, bool BN>
__global__ __launch_bounds__(256) void gat_project_tiled(
    const float* __restrict__ act, const float* __restrict__ scsh,
    const float* __restrict__ W,
    const float* __restrict__ att_s, const float* __restrict__ att_d,
    __half2* __restrict__ hb, float* __restrict__ as_,
    float* __restrict__ ad_, int n) {
  constexpr int AST = K + 4;
  __shared__ float aS[64 * AST];
  __shared__ float wS[K * 128];
  __shared__ float attS[256];

  int t = threadIdx.x;
  int node0 = blockIdx.x * 64;
  int rows = min(64, n - node0);

  constexpr int AF4 = 64 * K / 4;
  for (int i = t; i < AF4; i += 256) {
    int r = i / (K / 4), kc = i % (K / 4);
    float4 v = make_float4(0.f, 0.f, 0.f, 0.f);
    if (r < rows) v = *(const float4*)&act[(size_t)(node0 + r) * K + kc * 4];
    if (BN) {
      float4 sc4 = *(const float4*)&scsh[kc * 4];
      float4 sh4 = *(const float4*)&scsh[64 + kc * 4];
      v.x = fmaxf(fmaf(v.x, sc4.x, sh4.x), 0.f);
      v.y = fmaxf(fmaf(v.y, sc4.y, sh4.y), 0.f);
      v.z = fmaxf(fmaf(v.z, sc4.z, sh4.z), 0.f);
      v.w = fmaxf(fmaf(v.w, sc4.w, sh4.w), 0.f);
    }
    *(float4*)&aS[r * AST + kc * 4] = v;
  }
  constexpr int WF4 = K * 32;
  for (int i = t; i < WF4; i += 256)
    *(float4*)&wS[i * 4] = *(const float4*)&W[i * 4];
  attS[t] = (t < 128) ? att_s[t] : att_d[t - 128];
  __syncthreads();

  int tc = t & 15, tr = t >> 4;
  int c0 = tc * 8, r0 = tr * 4;

  float acc[4][8] = {};
  for (int k = 0; k < K; k += 4) {
    float4 av[4];
    float4 wv[4][2];
#pragma unroll
    for (int i = 0; i < 4; i++) av[i] = *(const float4*)&aS[(r0 + i) * AST + k];
#pragma unroll
    for (int kk = 0; kk < 4; kk++) {
      wv[kk][0] = *(const float4*)&wS[(k + kk) * 128 + c0];
      wv[kk][1] = *(const float4*)&wS[(k + kk) * 128 + c0 + 4];
    }
#pragma unroll
    for (int i = 0; i < 4; i++) {
      const float* ai = (const float*)&av[i];
#pragma unroll
      for (int kk = 0; kk < 4; kk++) {
        const float* w0 = (const float*)&wv[kk][0];
        const float* w1 = (const float*)&wv[kk][1];
#pragma unroll
        for (int j = 0; j < 4; j++) {
          acc[i][j] = fmaf(ai[kk], w0[j], acc[i][j]);
          acc[i][4 + j] = fmaf(ai[kk], w1[j], acc[i][4 + j]);
        }
      }
    }
  }

#pragma unroll
  for (int i = 0; i < 4; i++) {
    int r = r0 + i;
    float psv = 0.f, pdv = 0.f;
#pragma unroll
    for (int j = 0; j < 8; j++) {
      psv = fmaf(acc[i][j], attS[c0 + j], psv);
      pdv = fmaf(acc[i][j], attS[128 + c0 + j], pdv);
    }
    psv += __shfl_xor(psv, 1); pdv += __shfl_xor(pdv, 1);
    psv += __shfl_xor(psv, 2); pdv += __shfl_xor(pdv, 2);
    psv += __shfl_xor(psv, 4); pdv += __shfl_xor(pdv, 4);
    if (r < rows) {
      size_t base = (size_t)(node0 + r) * 64 + (c0 >> 1);
      hb[base + 0] = __floats2half2_rn(acc[i][0], acc[i][1]);
      hb[base + 1] = __floats2half2_rn(acc[i][2], acc[i][3]);
      hb[base + 2] = __floats2half2_rn(acc[i][4], acc[i][5]);
      hb[base + 3] = __floats2half2_rn(acc[i][6], acc[i][7]);
      if (tc == 0 || tc == 8) {
        int head = tc >> 3;
        as_[(node0 + r) * 2 + head] = psv;
        ad_[(node0 + r) * 2 + head] = pdv;
      }
    }
  }
}

// ---------------- GAT aggregation: wave per node ----------------------------
// 4 edges/group, 16 lanes/edge (sub = lane>>4, q = lane&15, 8 ch/lane).
// Two groups pipelined per iteration. Scores computed inline:
// my = exp(leaky(as_[s*2+hidx] + ad_my)), as_ is L2-resident (800 KB).
__device__ __forceinline__ void fma8(float* a, float my, uint4 raw) {
  float2 f;
  f = __half22float2(__builtin_bit_cast(__half2, raw.x)); a[0] = fmaf(my, f.x, a[0]); a[1] = fmaf(my, f.y, a[1]);
  f = __half22float2(__builtin_bit_cast(__half2, raw.y)); a[2] = fmaf(my, f.x, a[2]); a[3] = fmaf(my, f.y, a[3]);
  f = __half22float2(__builtin_bit_cast(__half2, raw.z)); a[4] = fmaf(my, f.x, a[4]); a[5] = fmaf(my, f.y, a[5]);
  f = __half22float2(__builtin_bit_cast(__half2, raw.w)); a[6] = fmaf(my, f.x, a[6]); a[7] = fmaf(my, f.y, a[7]);
}

__global__ __launch_bounds__(256) void gat_aggregate(
    const __half2* __restrict__ hb,
    const float* __restrict__ as_, const float* __restrict__ ad_,
    const int* __restrict__ row_ptr, const int2* __restrict__ col2,
    const float* __restrict__ bias, float* __restrict__ out, int n) {
  int wave = (int)((blockIdx.x * blockDim.x + threadIdx.x) >> 6);
  int lane = threadIdx.x & 63;
  if (wave >= n) return;
  int d = wave;
  int sub = lane >> 4, q = lane & 15;
  bool head1 = (q >= 8);
  int hidx = head1 ? 1 : 0;
  int beg = row_ptr[d], end = row_ptr[d + 1];
  const uint4* hb4 = (const uint4*)hb;   // 16 uint4 per node (256 B)

  // per-wave-uniform dst score term for this lane's head
  float2 dv = *(const float2*)&ad_[d * 2];
  float ad_my = head1 ? dv.y : dv.x;

  float a[8] = {};
  float dpart = 0.f;

  if (sub == 0) {  // self-loop (not in CSR)
    float asv = as_[d * 2 + hidx];
    float my = __expf(leaky(asv + ad_my));
    uint4 raw = hb4[(size_t)d * 16 + q];
    fma8(a, my, raw);
    dpart = my;
  }

  int k = beg;
  // 2 groups of 4 edges per iteration, all gathers issued before the math
  for (; k + 7 < end; k += 8) {
    int kkA = k + sub, kkB = k + 4 + sub;
    int sA = col2[kkA].x;
    int sB = col2[kkB].x;
    float asA = as_[sA * 2 + hidx];
    float asB = as_[sB * 2 + hidx];
    uint4 rawA = hb4[(size_t)sA * 16 + q];
    uint4 rawB = hb4[(size_t)sB * 16 + q];
    float myA = __expf(leaky(asA + ad_my));
    float myB = __expf(leaky(asB + ad_my));
    fma8(a, myA, rawA);
    dpart += myA;
    fma8(a, myB, rawB);
    dpart += myB;
  }
  if (k + 3 < end) {  // one full group of 4
    int kk = k + sub;
    int s = col2[kk].x;
    float asv = as_[s * 2 + hidx];
    uint4 raw = hb4[(size_t)s * 16 + q];
    float my = __expf(leaky(asv + ad_my));
    fma8(a, my, raw);
    dpart += my;
    k += 4;
  }
  int rem = end - k;
  if (sub < rem) {  // remainder 0..3
    int kk = k + sub;
    int s = col2[kk].x;
    float asv = as_[s * 2 + hidx];
    uint4 raw = hb4[(size_t)s * 16 + q];
    float my = __expf(leaky(asv + ad_my));
    fma8(a, my, raw);
    dpart += my;
  }

  // butterfly combine across the 4 sub groups (same q)
#pragma unroll
  for (int i = 0; i < 8; i++) a[i] += __shfl(a[i], lane ^ 16);
  dpart += __shfl(dpart, lane ^ 16);
#pragma unroll
  for (int i = 0; i < 8; i++) a[i] += __shfl(a[i], lane ^ 32);
  float dsum = dpart + __shfl(dpart, lane ^ 32);

  // head-1 values for lane q (<8) live at lane q+8 (same sub group)
  int src = (lane + 8) & 63;
  float b[8];
#pragma unroll
  for (int i = 0; i < 8; i++) b[i] = __shfl(a[i], src);
  float den1 = __shfl(dsum, src);
  if (lane < 8) {  // sub 0, q 0..7: output channels 8q..8q+7
    float r0 = 1.f / (dsum + 1e-16f), r1 = 1.f / (den1 + 1e-16f);
    float4 bl = *(const float4*)&bias[q * 8];
    float4 bh = *(const float4*)&bias[q * 8 + 4];
    float4 o0, o1;
    o0.x = 0.5f * (a[0] * r0 + b[0] * r1) + bl.x;
    o0.y = 0.5f * (a[1] * r0 + b[1] * r1) + bl.y;
    o0.z = 0.5f * (a[2] * r0 + b[2] * r1) + bl.z;
    o0.w = 0.5f * (a[3] * r0 + b[3] * r1) + bl.w;
    o1.x = 0.5f * (a[4] * r0 + b[4] * r1) + bh.x;
    o1.y = 0.5f * (a[5] * r0 + b[5] * r1) + bh.y;
    o1.z = 0.5f * (a[6] * r0 + b[6] * r1) + bh.z;
    o1.w = 0.5f * (a[7] * r0 + b[7] * r1) + bh.w;
    *(float4*)&out[(size_t)d * 64 + q * 8] = o0;
    *(float4*)&out[(size_t)d * 64 + q * 8 + 4] = o1;
  }
}

// ---------------- MLP head: fused tiled GEMM (64 nodes / block) --------------
// a1 staging applies BN(layer3 scsh)+ReLU to the raw aggregate output.
__global__ __launch_bounds__(256) void mlp_head_tiled(
    const float* __restrict__ h3raw, const float* __restrict__ scsh,
    const float* __restrict__ x,
    const float* __restrict__ mW1, const float* __restrict__ mb1,
    const float* __restrict__ mW2, const float* __restrict__ mb2,
    const float* __restrict__ pW, const float* __restrict__ pb,
    const float* __restrict__ vW, const float* __restrict__ vb,
    float* __restrict__ out, int n) {
  __shared__ float lds[13632];
  float* a1  = lds;           // 64*68 = 4352
  float* ctx = lds + 4352;    // 64*8  = 512
  float* a2  = lds + 4864;    // 64*68 = 4352
  float* w1  = lds + 9216;    // 69*64 = 4416
  float* w2  = lds;           // aliases a1 (dead after GEMM1)

  int t = threadIdx.x;
  int node0 = blockIdx.x * 64;
  int rows = min(64, n - node0);

#pragma unroll
  for (int i = 0; i < 4; i++) {
    int flat = t + i * 256;
    int r = flat >> 4, kc = flat & 15;
    float4 v = make_float4(0.f, 0.f, 0.f, 0.f);
    if (r < rows) v = *(const float4*)&h3raw[(size_t)(node0 + r) * 64 + kc * 4];
    float4 sc4 = *(const float4*)&scsh[kc * 4];
    float4 sh4 = *(const float4*)&scsh[64 + kc * 4];
    v.x = fmaxf(fmaf(v.x, sc4.x, sh4.x), 0.f);
    v.y = fmaxf(fmaf(v.y, sc4.y, sh4.y), 0.f);
    v.z = fmaxf(fmaf(v.z, sc4.z, sh4.z), 0.f);
    v.w = fmaxf(fmaf(v.w, sc4.w, sh4.w), 0.f);
    *(float4*)&a1[r * 68 + kc * 4] = v;
  }
  for (int i = t; i < 320; i += 256) {
    int r = i / 5, j = i % 5;
    ctx[r * 8 + j] = (r < rows) ? x[(size_t)(node0 + r) * 16 + 9 + j] : 0.f;
  }
#pragma unroll
  for (int i = 0; i < 5; i++) {
    int flat = t + i * 256;
    if (flat < 1104) *(float4*)&w1[flat * 4] = *(const float4*)&mW1[flat * 4];
  }
  __syncthreads();

  int tc = t & 15, tr = t >> 4;
  int c0 = tc * 4, r0 = tr * 4;

  float acc[4][4] = {};
  for (int k = 0; k < 64; k += 4) {
    float4 av[4], wv[4];
#pragma unroll
    for (int i = 0; i < 4; i++) av[i] = *(const float4*)&a1[(r0 + i) * 68 + k];
#pragma unroll
    for (int j = 0; j < 4; j++) wv[j] = *(const float4*)&w1[(k + j) * 64 + c0];
#pragma unroll
    for (int i = 0; i < 4; i++) {
      const float* ai = (const float*)&av[i];
#pragma unroll
      for (int kk = 0; kk < 4; kk++) {
        const float* wr = (const float*)&wv[kk];
        acc[i][0] = fmaf(ai[kk], wr[0], acc[i][0]);
        acc[i][1] = fmaf(ai[kk], wr[1], acc[i][1]);
        acc[i][2] = fmaf(ai[kk], wr[2], acc[i][2]);
        acc[i][3] = fmaf(ai[kk], wr[3], acc[i][3]);
      }
    }
  }
#pragma unroll
  for (int k = 64; k < 69; k++) {
    float4 wv = *(const float4*)&w1[k * 64 + c0];
    const float* wr = (const float*)&wv;
#pragma unroll
    for (int i = 0; i < 4; i++) {
      float a = ctx[(r0 + i) * 8 + (k - 64)];
      acc[i][0] = fmaf(a, wr[0], acc[i][0]);
      acc[i][1] = fmaf(a, wr[1], acc[i][1]);
      acc[i][2] = fmaf(a, wr[2], acc[i][2]);
      acc[i][3] = fmaf(a, wr[3], acc[i][3]);
    }
  }
  float b1v0 = mb1[c0], b1v1 = mb1[c0 + 1], b1v2 = mb1[c0 + 2], b1v3 = mb1[c0 + 3];
#pragma unroll
  for (int i = 0; i < 4; i++) {
    float4 t1;
    t1.x = fmaxf(acc[i][0] + b1v0, 0.f);
    t1.y = fmaxf(acc[i][1] + b1v1, 0.f);
    t1.z = fmaxf(acc[i][2] + b1v2, 0.f);
    t1.w = fmaxf(acc[i][3] + b1v3, 0.f);
    *(float4*)&a2[(r0 + i) * 68 + c0] = t1;
  }
  __syncthreads();

#pragma unroll
  for (int i = 0; i < 4; i++) {
    int flat = t + i * 256;
    *(float4*)&w2[flat * 4] = *(const float4*)&mW2[flat * 4];
  }
  __syncthreads();

  float acc2[4][4] = {};
  for (int k = 0; k < 64; k += 4) {
    float4 av[4], wv[4];
#pragma unroll
    for (int i = 0; i < 4; i++) av[i] = *(const float4*)&a2[(r0 + i) * 68 + k];
#pragma unroll
    for (int j = 0; j < 4; j++) wv[j] = *(const float4*)&w2[(k + j) * 64 + c0];
#pragma unroll
    for (int i = 0; i < 4; i++) {
      const float* ai = (const float*)&av[i];
#pragma unroll
      for (int kk = 0; kk < 4; kk++) {
        const float* wr = (const float*)&wv[kk];
        acc2[i][0] = fmaf(ai[kk], wr[0], acc2[i][0]);
        acc2[i][1] = fmaf(ai[kk], wr[1], acc2[i][1]);
        acc2[i][2] = fmaf(ai[kk], wr[2], acc2[i][2]);
        acc2[i][3] = fmaf(ai[kk], wr[3], acc2[i][3]);
      }
    }
  }

  float b2v[4], pwv[4], vwv[4];
#pragma unroll
  for (int j = 0; j < 4; j++) {
    b2v[j] = mb2[c0 + j];
    pwv[j] = pW[c0 + j];
    vwv[j] = vW[c0 + j];
  }
  float p[4], v[4];
#pragma unroll
  for (int i = 0; i < 4; i++) {
    float ps = 0.f, vs = 0.f;
#pragma unroll
    for (int j = 0; j < 4; j++) {
      float u = acc2[i][j] + b2v[j];
      ps = fmaf(u, pwv[j], ps);
      vs = fmaf(u, vwv[j], vs);
    }
    p[i] = ps; v[i] = vs;
  }
#pragma unroll
  for (int off = 1; off < 16; off <<= 1) {
#pragma unroll
    for (int i = 0; i < 4; i++) {
      p[i] += __shfl_xor(p[i], off);
      v[i] += __shfl_xor(v[i], off);
    }
  }
  if (tc == 0) {
    float pbs = pb[0], vbs = vb[0];
#pragma unroll
    for (int i = 0; i < 4; i++) {
      int r = r0 + i;
      if (r < rows) {
        out[node0 + r] = p[i] + pbs;
        out[n + node0 + r] = v[i] + vbs;
      }
    }
  }
}

extern "C" void kernel_launch(void* const* d_in, const int* in_sizes, int n_in,
                              void* d_out, int out_size, void* d_ws, size_t ws_size,
                              hipStream_t stream) {
  const float* x = (const float*)d_in[0];
  const int* ei = (const int*)d_in[1];
  const float* W[3]  = {(const float*)d_in[2],  (const float*)d_in[8],  (const float*)d_in[14]};
  const float* AS[3] = {(const float*)d_in[3],  (const float*)d_in[9],  (const float*)d_in[15]};
  const float* AD[3] = {(const float*)d_in[4],  (const float*)d_in[10], (const float*)d_in[16]};
  const float* B[3]  = {(const float*)d_in[5],  (const float*)d_in[11], (const float*)d_in[17]};
  const float* G[3]  = {(const float*)d_in[6],  (const float*)d_in[12], (const float*)d_in[18]};
  const float* BE[3] = {(const float*)d_in[7],  (const float*)d_in[13], (const float*)d_in[19]};
  const float* mW1 = (const float*)d_in[20];
  const float* mb1 = (const float*)d_in[21];
  const float* mW2 = (const float*)d_in[22];
  const float* mb2 = (const float*)d_in[23];
  const float* pW  = (const float*)d_in[24];
  const float* pb  = (const float*)d_in[25];
  const float* vW  = (const float*)d_in[26];
  const float* vb  = (const float*)d_in[27];

  const int N = in_sizes[0] / 16;
  const int E = in_sizes[1] / 2;
  const int* srcp = ei;
  const int* dstp = ei + E;

  // workspace carve-up (~70 MB)
  float* bufB  = (float*)d_ws;               // N*64  raw aggregate output
  float* hbuf  = bufB + (size_t)N * 64;      // N*64 half2 region (N*64 f32 bytes)
  float* as_   = hbuf + (size_t)N * 64;      // N*2
  float* ad_   = as_ + (size_t)N * 2;        // N*2
  float* stats = ad_ + (size_t)N * 2;        // 128
  float* scsh  = stats + 128;                // 128
  int* row_ptr = (int*)(scsh + 128);         // N+1
  int* bcnt    = row_ptr + (N + 1);          // 512
  int* boff    = bcnt + 512;                 // 512
  int* bcur    = boff + 512;                 // 512
  int2* col2   = (int2*)(bcur + 512);        // E int2 (sorted CSR)
  int2* ebuf   = col2 + E;                   // E int2 (staging)
  __half2* hb  = (__half2*)hbuf;

  const int nbk = (N + 255) >> 8;
  const float inv_n = 1.0f / (float)N;

  // ---- CSR build: binned counting sort
  hipMemsetAsync(bcnt, 0, sizeof(int) * 512, stream);
  bucket_hist<<<256, 256, 0, stream>>>(dstp, bcnt, E);
  bucket_scan<<<1, 512, 0, stream>>>(bcnt, boff, bcur, nbk);
  bin_scatter<<<(E + 8191) / 8192, 256, 0, stream>>>(srcp, dstp, bcur, ebuf, E);
  bucket_sort<<<nbk, 256, 0, stream>>>(ebuf, boff, col2, row_ptr, E, N, nbk);

  const int tiles = (N + 63) / 64;

  // ---- 3 GAT layers (BN+ReLU fused into the next consumer via scsh)
  for (int l = 0; l < 3; l++) {
    if (l == 0)
      gat_project_tiled<16, false><<<tiles, 256, 0, stream>>>(x, scsh, W[l], AS[l], AD[l],
                                                              hb, as_, ad_, N);
    else
      gat_project_tiled<64, true><<<tiles, 256, 0, stream>>>(bufB, scsh, W[l], AS[l], AD[l],
                                                             hb, as_, ad_, N);
    gat_aggregate<<<(N + 3) / 4, 256, 0, stream>>>(hb, as_, ad_, row_ptr, col2,
                                                   B[l], bufB, N);
    hipMemsetAsync(stats, 0, sizeof(float) * 128, stream);
    bn_stats<<<1024, 256, 0, stream>>>(bufB, stats, N);
    bn_finalize<<<1, 64, 0, stream>>>(stats, G[l], BE[l], scsh, inv_n);
  }

  // ---- MLP head -> (logits, value); applies layer-3 BN+ReLU to bufB
  mlp_head_tiled<<<tiles, 256, 0, stream>>>(bufB, scsh, x, mW1, mb1, mW2, mb2,
                                            pW, pb, vW, vb, (float*)d_out, N);
}